// Round 3
// baseline (4607.103 us; speedup 1.0000x reference)
//
#include <hip/hip_runtime.h>
#include <hip/hip_bf16.h>

typedef unsigned short u16;
typedef __attribute__((ext_vector_type(8))) short bf16x8;
typedef __attribute__((ext_vector_type(4))) float f32x4;

typedef __attribute__((address_space(1))) const void gv_t;  // global
typedef __attribute__((address_space(3))) void lv_t;        // LDS

#define DEVINL __device__ __forceinline__

DEVINL float bf2f(u16 s) { union { unsigned u; float f; } v; v.u = ((unsigned)s) << 16; return v.f; }
DEVINL u16 f2bf(float f) {
  union { float f; unsigned u; } v; v.f = f;
  return (u16)((v.u + 0x7FFFu + ((v.u >> 16) & 1u)) >> 16);
}

// ---- ws probe (reports ws_size via absmax when workspace too small) ----
__global__ void probe_k(float* __restrict__ out, float v) { out[threadIdx.x] = v; }

// ---- BT[n*dstK + koff + k] = bf16(scale * sum_r W[(r*512+k)*512+n]) ----
__global__ void pack_wt(const float* __restrict__ W, int r0, int r1, int r2, int r3,
                        u16* __restrict__ dst, int dstK, int koff, float scale) {
  int idx = blockIdx.x * 256 + threadIdx.x;
  if (idx >= 512 * 512) return;
  int k = idx >> 9, n = idx & 511;
  float v = W[((size_t)r0 * 512 + k) * 512 + n];
  if (r1 >= 0) v += W[((size_t)r1 * 512 + k) * 512 + n];
  if (r2 >= 0) v += W[((size_t)r2 * 512 + k) * 512 + n];
  if (r3 >= 0) v += W[((size_t)r3 * 512 + k) * 512 + n];
  dst[(size_t)n * dstK + koff + k] = f2bf(v * scale);
}

// ---- BT[n*K + koff + f] = bf16(scale * sum_k A[f*512+k] * sum_r W[(r*512+k)*512+n]) ----
__global__ void fold_bt(const float* __restrict__ A, int F, const float* __restrict__ W,
                        int r0, int r1, int r2, int r3, float scale,
                        u16* __restrict__ BT, int K, int koff) {
  int idx = blockIdx.x * 256 + threadIdx.x;
  int f = idx >> 9, n = idx & 511;
  if (f >= F) return;
  float a = 0.f;
  for (int k = 0; k < 512; ++k) {
    float w = W[((size_t)r0 * 512 + k) * 512 + n];
    if (r1 >= 0) w += W[((size_t)r1 * 512 + k) * 512 + n];
    if (r2 >= 0) w += W[((size_t)r2 * 512 + k) * 512 + n];
    if (r3 >= 0) w += W[((size_t)r3 * 512 + k) * 512 + n];
    a += A[(size_t)f * 512 + k] * w;
  }
  BT[(size_t)n * K + koff + f] = f2bf(a * scale);
}

// ---- out[n] = blscale*sum(bl_i[n]) + bscale*sum_k bvec[k]*sum_r W[(r*512+k)*512+n] ----
__global__ void vec_foldbias(const float* __restrict__ bl, int i0, int i1, int i2, int i3,
                             float blscale, const float* __restrict__ bvec,
                             const float* __restrict__ W, int j0, int j1, int j2, int j3,
                             float bscale, float* __restrict__ out) {
  int n = blockIdx.x * 256 + threadIdx.x;
  if (n >= 512) return;
  float v = 0.f;
  if (bl) {
    v = bl[i0 * 512 + n];
    if (i1 >= 0) v += bl[i1 * 512 + n];
    if (i2 >= 0) v += bl[i2 * 512 + n];
    if (i3 >= 0) v += bl[i3 * 512 + n];
    v *= blscale;
  }
  if (bvec) {
    float a = 0.f;
    for (int k = 0; k < 512; ++k) {
      float w = W[((size_t)j0 * 512 + k) * 512 + n];
      if (j1 >= 0) w += W[((size_t)j1 * 512 + k) * 512 + n];
      if (j2 >= 0) w += W[((size_t)j2 * 512 + k) * 512 + n];
      if (j3 >= 0) w += W[((size_t)j3 * 512 + k) * 512 + n];
      a += bvec[k] * w;
    }
    v += bscale * a;
  }
  out[n] = v;
}

// ---- CSR build ----
__global__ void hist_k(const int* __restrict__ dst, int nE, int* __restrict__ cnt) {
  int i = blockIdx.x * 256 + threadIdx.x;
  if (i < nE) atomicAdd(&cnt[dst[i]], 1);
}

__global__ void hist_range(const int* __restrict__ dst, const int* __restrict__ src, int nE,
                           int* __restrict__ cnt, int s0, int s1) {
  int i = blockIdx.x * 256 + threadIdx.x;
  if (i < nE) {
    int s = src[i];
    if (s >= s0 && s < s1) atomicAdd(&cnt[dst[i]], 1);
  }
}

__global__ void scan1_k(const int* __restrict__ in, int* __restrict__ out,
                        int* __restrict__ part, int n) {
  __shared__ int s[256];
  int t = threadIdx.x;
  int base = blockIdx.x * 1024 + t * 4;
  int x0 = 0, x1 = 0, x2 = 0, x3 = 0;
  if (base < n) x0 = in[base];
  if (base + 1 < n) x1 = in[base + 1];
  if (base + 2 < n) x2 = in[base + 2];
  if (base + 3 < n) x3 = in[base + 3];
  int tsum = x0 + x1 + x2 + x3;
  s[t] = tsum;
  __syncthreads();
  for (int off = 1; off < 256; off <<= 1) {
    int v = (t >= off) ? s[t - off] : 0;
    __syncthreads();
    s[t] += v;
    __syncthreads();
  }
  int excl = s[t] - tsum;
  if (base < n) out[base] = excl;
  if (base + 1 < n) out[base + 1] = excl + x0;
  if (base + 2 < n) out[base + 2] = excl + x0 + x1;
  if (base + 3 < n) out[base + 3] = excl + x0 + x1 + x2;
  if (t == 255) part[blockIdx.x] = s[255];
}

__global__ void scan2_k(int* __restrict__ part, int nb) {
  __shared__ int s[1024];
  int t = threadIdx.x;
  int orig = (t < nb) ? part[t] : 0;
  s[t] = orig;
  __syncthreads();
  for (int off = 1; off < 1024; off <<= 1) {
    int v = (t >= off) ? s[t - off] : 0;
    __syncthreads();
    s[t] += v;
    __syncthreads();
  }
  if (t < nb) part[t] = s[t] - orig;
}

__global__ void scan3_k(int* __restrict__ out, int* __restrict__ cursor,
                        const int* __restrict__ part, int n) {
  int i = blockIdx.x * 256 + threadIdx.x;
  if (i < n) {
    int v = out[i] + part[i >> 10];
    out[i] = v;
    cursor[i] = v;
  }
}

__global__ void fill_range(const int* __restrict__ src, const int* __restrict__ dst, int nE,
                           int* __restrict__ cursor, int* __restrict__ esrc, int s0, int s1) {
  int i = blockIdx.x * 256 + threadIdx.x;
  if (i >= nE) return;
  int s = src[i];
  if (s >= s0 && s < s1) {
    int pos = atomicAdd(&cursor[dst[i]], 1);
    esrc[pos] = s - s0;
  }
}

// ---- raw-feature segment mean + indicator (8 threads per dst row) ----
__global__ void raw_agg(const int* __restrict__ offs, const int* __restrict__ esrc,
                        const float* __restrict__ x, int F, u16* __restrict__ A1,
                        int K, int colOff, int indCol, int nd) {
  int row = blockIdx.x * 32 + (threadIdx.x >> 3);
  if (row >= nd) return;
  int j = threadIdx.x & 7;
  int e0 = offs[row], e1 = offs[row + 1];
  float acc[4] = {0.f, 0.f, 0.f, 0.f};
  for (int e = e0; e < e1; ++e) {
    int s = esrc[e];
#pragma unroll
    for (int u = 0; u < 4; ++u) {
      int f = j + u * 8;
      if (f < F) acc[u] += x[(size_t)s * F + f];
    }
  }
  float inv = (e1 > e0) ? 1.f / (float)(e1 - e0) : 0.f;
#pragma unroll
  for (int u = 0; u < 4; ++u) {
    int f = j + u * 8;
    if (f < F) A1[(size_t)row * K + colOff + f] = f2bf(acc[u] * inv);
  }
  if (j == 0) A1[(size_t)row * K + indCol] = f2bf((e1 > e0) ? 1.f : 0.f);
}

// ---- copy root raw features into A1 ----
__global__ void a1_root(const float* __restrict__ x, int rowBase, u16* __restrict__ A1,
                        int K, int rootOff, int nd, int lf) {
  int idx = blockIdx.x * 256 + threadIdx.x;
  int i = idx >> lf, f = idx & ((1 << lf) - 1);
  if (i >= nd) return;
  A1[(size_t)i * K + rootOff + f] = f2bf(x[(((size_t)(rowBase + i)) << lf) + f]);
}

// ---- gather partial segment-sums scaled by 1/full-count (wave per dst row) ----
__global__ void seg_gather(const int* __restrict__ offsF, const int* __restrict__ offsS,
                           const int* __restrict__ esrcF, const u16* __restrict__ hsrc,
                           u16* __restrict__ agg, int nd) {
  int w = blockIdx.x * 4 + (threadIdx.x >> 6);
  if (w >= nd) return;
  int l = threadIdx.x & 63;
  int e0 = offsF[w], e1 = offsF[w + 1];
  int c0 = offsS[w], c1 = offsS[w + 1];
  float inv = (c1 > c0) ? 1.f / (float)(c1 - c0) : 0.f;
  float acc[8] = {0.f, 0.f, 0.f, 0.f, 0.f, 0.f, 0.f, 0.f};
  for (int e = e0; e < e1; ++e) {
    int s = esrcF[e];
    bf16x8 v = *(const bf16x8*)&hsrc[(size_t)s * 512 + l * 8];
#pragma unroll
    for (int j = 0; j < 8; ++j) acc[j] += bf2f((u16)v[j]);
  }
  bf16x8 r;
#pragma unroll
  for (int j = 0; j < 8; ++j) r[j] = (short)f2bf(acc[j] * inv);
  *(bf16x8*)&agg[(size_t)w * 512 + l * 8] = r;
}

// ---- MFMA GEMM: C[M][512] (+)= op(A[M][K] @ BT[512][K]^T + bias), bf16 ----
template <bool ELU, bool ACC>
__global__ __launch_bounds__(256) void gemm_k(
    const u16* __restrict__ A, int K, const u16* __restrict__ BT,
    const float* __restrict__ bias, u16* __restrict__ C, int M) {
  __shared__ u16 As[128 * 64];
  __shared__ u16 Bs[128 * 64];
  int tid = threadIdx.x;
  int wid = tid >> 6, lane = tid & 63;
  int wm = wid >> 1, wn = wid & 1;
  int bm = blockIdx.x * 128, bn = blockIdx.y * 128;
  int r16 = lane & 15, hi4 = lane >> 4;
  int srow = tid >> 3, scol = (tid & 7) * 8;
  f32x4 acc[4][4];
#pragma unroll
  for (int i = 0; i < 4; ++i)
#pragma unroll
    for (int j = 0; j < 4; ++j) acc[i][j] = (f32x4){0.f, 0.f, 0.f, 0.f};

  for (int k0 = 0; k0 < K; k0 += 64) {
    __syncthreads();
#pragma unroll
    for (int i = 0; i < 4; ++i) {
      const u16* ga = A + (size_t)(bm + i * 32 + srow) * K + k0 + scol;
      const u16* gb = BT + (size_t)(bn + i * 32 + srow) * K + k0 + scol;
      __builtin_amdgcn_global_load_lds((gv_t*)ga, (lv_t*)(As + i * 2048 + wid * 512), 16, 0, 0);
      __builtin_amdgcn_global_load_lds((gv_t*)gb, (lv_t*)(Bs + i * 2048 + wid * 512), 16, 0, 0);
    }
    __syncthreads();
#pragma unroll
    for (int kk = 0; kk < 64; kk += 32) {
      bf16x8 af[4], bfr[4];
#pragma unroll
      for (int f = 0; f < 4; ++f) {
        af[f]  = *(const bf16x8*)&As[(wm * 64 + f * 16 + r16) * 64 + kk + hi4 * 8];
        bfr[f] = *(const bf16x8*)&Bs[(wn * 64 + f * 16 + r16) * 64 + kk + hi4 * 8];
      }
#pragma unroll
      for (int mf = 0; mf < 4; ++mf)
#pragma unroll
        for (int nf = 0; nf < 4; ++nf)
          acc[mf][nf] = __builtin_amdgcn_mfma_f32_16x16x32_bf16(af[mf], bfr[nf], acc[mf][nf], 0, 0, 0);
    }
  }
#pragma unroll
  for (int mf = 0; mf < 4; ++mf) {
#pragma unroll
    for (int nf = 0; nf < 4; ++nf) {
      int c = bn + wn * 64 + nf * 16 + r16;
      float bv = bias ? bias[c] : 0.f;
#pragma unroll
      for (int j = 0; j < 4; ++j) {
        int r = bm + wm * 64 + mf * 16 + hi4 * 4 + j;
        float v = acc[mf][nf][j] + bv;
        if (ACC) v += bf2f(C[(size_t)r * 512 + c]);
        if (ELU) v = v > 0.f ? v : expm1f(v);
        C[(size_t)r * 512 + c] = f2bf(v);
      }
    }
  }
}

// ---- acc init: broadcast bias vector ----
__global__ void bcast_k(u16* __restrict__ acc, const float* __restrict__ bv, int rows) {
  int idx = blockIdx.x * 256 + threadIdx.x;
  int row = idx >> 6, c8 = (idx & 63) * 8;
  if (row >= rows) return;
  bf16x8 r;
#pragma unroll
  for (int j = 0; j < 8; ++j) r[j] = (short)f2bf(bv[c8 + j]);
  *(bf16x8*)&acc[(size_t)row * 512 + c8] = r;
}

// ---- LayerNorm in place (optional ELU first); wave per row ----
template <bool ELU>
__global__ void ln_rows(u16* __restrict__ H, const float* __restrict__ g,
                        const float* __restrict__ be, int rows) {
  int w = blockIdx.x * 4 + (threadIdx.x >> 6);
  if (w >= rows) return;
  int l = threadIdx.x & 63;
  u16* p = H + (size_t)w * 512 + l * 8;
  bf16x8 v = *(const bf16x8*)p;
  float x[8];
  float s = 0.f;
#pragma unroll
  for (int j = 0; j < 8; ++j) {
    x[j] = bf2f((u16)v[j]);
    if (ELU) x[j] = x[j] > 0.f ? x[j] : expm1f(x[j]);
    s += x[j];
  }
#pragma unroll
  for (int m = 1; m < 64; m <<= 1) s += __shfl_xor(s, m, 64);
  float mean = s * (1.f / 512.f);
  float q = 0.f;
#pragma unroll
  for (int j = 0; j < 8; ++j) { float d = x[j] - mean; q += d * d; }
#pragma unroll
  for (int m = 1; m < 64; m <<= 1) q += __shfl_xor(q, m, 64);
  float rsd = rsqrtf(q * (1.f / 512.f) + 1e-5f);
  bf16x8 r;
#pragma unroll
  for (int j = 0; j < 8; ++j) {
    int c = l * 8 + j;
    r[j] = (short)f2bf((x[j] - mean) * rsd * g[c] + be[c]);
  }
  *(bf16x8*)p = r;
}

// ---- pooling ----
DEVINL int lowb(const int* a, int n, int v) {
  int lo = 0, hi = n;
  while (lo < hi) { int m = (lo + hi) >> 1; if (a[m] < v) lo = m + 1; else hi = m; }
  return lo;
}

__global__ void pool1(const u16* __restrict__ H, const int* __restrict__ batch, int nOp,
                      float* __restrict__ pooled, int* __restrict__ cnts) {
  int g = blockIdx.x >> 3, part = blockIdx.x & 7;
  int lo = lowb(batch, nOp, g), hi = lowb(batch, nOp, g + 1);
  if (part == 0 && threadIdx.x == 0) cnts[g] = hi - lo;
  int len = hi - lo;
  int chunk = (len + 7) >> 3;
  int r0 = lo + part * chunk;
  int r1 = r0 + chunk;
  if (r1 > hi) r1 = hi;
  int t = threadIdx.x;
  float a0 = 0.f, a1 = 0.f;
  for (int r = r0; r < r1; ++r) {
    a0 += bf2f(H[(size_t)r * 512 + t]);
    a1 += bf2f(H[(size_t)r * 512 + t + 256]);
  }
  atomicAdd(&pooled[g * 512 + t], a0);
  atomicAdd(&pooled[g * 512 + t + 256], a1);
}

__global__ void pool2(const float* __restrict__ pooled, const int* __restrict__ cnts,
                      const float* __restrict__ Wout, const float* __restrict__ bout,
                      float* __restrict__ out) {
  int gg = blockIdx.x;
  int l = threadIdx.x;
  float s = 0.f;
#pragma unroll
  for (int j = 0; j < 8; ++j) {
    int c = l * 8 + j;
    s += pooled[gg * 512 + c] * Wout[c];
  }
#pragma unroll
  for (int m = 1; m < 64; m <<= 1) s += __shfl_xor(s, m, 64);
  if (l == 0) {
    int c = cnts[gg];
    if (c < 1) c = 1;
    out[gg] = s / (float)c + bout[0];
  }
}

extern "C" void kernel_launch(void* const* d_in, const int* in_sizes, int n_in,
                              void* d_out, int out_size, void* d_ws, size_t ws_size,
                              hipStream_t stream) {
  (void)in_sizes; (void)n_in; (void)out_size;
  // inputs: node feats 0=op,1=tab,2=col,3=pred
  const float* x_op   = (const float*)d_in[0];
  const float* x_tab  = (const float*)d_in[1];
  const float* x_col  = (const float*)d_in[2];
  const float* x_pred = (const float*)d_in[3];
  const float* W_op = (const float*)d_in[4],  *b_op = (const float*)d_in[5];
  const float* W_tab = (const float*)d_in[6], *b_tab = (const float*)d_in[7];
  const float* W_col = (const float*)d_in[8], *b_col = (const float*)d_in[9];
  const float* W_pred = (const float*)d_in[10], *b_pred = (const float*)d_in[11];
  const float* Wl1 = (const float*)d_in[12];
  const float* bl1 = (const float*)d_in[13];
  const float* Wr1 = (const float*)d_in[14];
  const float* Wl2 = (const float*)d_in[15];
  const float* bl2 = (const float*)d_in[16];
  const float* Wr2 = (const float*)d_in[17];
  const float* g1  = (const float*)d_in[18];
  const float* be1 = (const float*)d_in[19];
  const float* g2  = (const float*)d_in[20];
  const float* be2 = (const float*)d_in[21];
  const float* Wout = (const float*)d_in[22];
  const float* bout = (const float*)d_in[23];
  const int* SRC[7], *DST[7];
  for (int r = 0; r < 7; ++r) { SRC[r] = (const int*)d_in[24 + 2 * r]; DST[r] = (const int*)d_in[25 + 2 * r]; }
  const int* batch = (const int*)d_in[38];
  float* out = (float*)d_out;

  const int EREL[7] = {262144, 262144, 262144, 262144, 262144, 32768, 131072};
  const int CSRB[7] = {0, 131072, 262144, 393216, 458752, 589824, 622592};
  const int TOT = 753664;
  const int NOP = 131072;

  // ---- workspace layout (256 MiB budget) ----
  char* ws = (char*)d_ws;
  u16* acc    = (u16*)ws;                            // 134,217,728 : conv2_op accumulator (bf16)
  u16* hsrc   = (u16*)(ws + 134217728ull);           //  67,108,864 : recomputed layer-1 h chunk
  u16* agg    = (u16*)(ws + 201326592ull);           //  33,554,432 : [32768x512] bf16 agg chunk
  int* curFul = (int*)(ws + 201326592ull);           //   (overlay in agg: CSR-build cursor)
  u16* A1     = (u16*)(ws + 234881024ull);           //  16,777,216 : [65536x128] bf16 features
  int* offsFul= (int*)(ws + 251658240ull);           //   3,014,912 : (TOT+1) offsets
  int* esrcFul= (int*)(ws + 254673152ull);           //   5,898,240
  int* offsF  = (int*)(ws + 260571392ull);           //     524,544 : filtered CSR (131073)
  int* curF   = (int*)(ws + 261095936ull);           //     524,544
  int* esrcF  = (int*)(ws + 261620480ull);           //   1,048,576
  u16* BT2_0  = (u16*)(ws + 262669056ull);           //   5x524,288 : layer-2 weights [512x512]
  u16* BT2_1  = BT2_0 + 262144;
  u16* BT2_2  = BT2_1 + 262144;
  u16* BT2_4  = BT2_2 + 262144;
  u16* BT2rt  = BT2_4 + 262144;
  u16* BT1op  = (u16*)(ws + 265290496ull);           //      65,536 : [512x64]
  u16* BT1tab = (u16*)(ws + 265356032ull);           //      65,536
  u16* BT1col = (u16*)(ws + 265421568ull);           //     131,072 : [512x128]
  u16* BT1pr  = (u16*)(ws + 265552640ull);           //      65,536
  float* b1op = (float*)(ws + 265618176ull);         //   5x2048 bias vecs
  float* b1tab = b1op + 512, *b1col = b1op + 1024, *b1pr = b1op + 1536, *b2vec = b1op + 2048;
  float* pooled = (float*)(ws + 265628416ull);       //     131,072
  int* cnts     = (int*)(ws + 265759488ull);         //         256
  int* part     = (int*)(ws + 265759744ull);         //       4,096
  const size_t WS_NEED = 265763840ull;
  if (ws_size < WS_NEED) { probe_k<<<1, 64, 0, stream>>>(out, (float)ws_size); return; }

  // ---- A. full CSR for all 7 relations ----
  hipMemsetAsync(curFul, 0, (size_t)(TOT + 1) * 4, stream);
  for (int r = 0; r < 7; ++r)
    hist_k<<<(EREL[r] + 255) / 256, 256, 0, stream>>>(DST[r], EREL[r], curFul + CSRB[r]);
  scan1_k<<<737, 256, 0, stream>>>(curFul, offsFul, part, TOT + 1);
  scan2_k<<<1, 1024, 0, stream>>>(part, 737);
  scan3_k<<<2945, 256, 0, stream>>>(offsFul, curFul, part, TOT + 1);
  for (int r = 0; r < 7; ++r)
    fill_range<<<(EREL[r] + 255) / 256, 256, 0, stream>>>(SRC[r], DST[r], EREL[r],
                                                          curFul + CSRB[r], esrcFul, 0, 1 << 30);

  // ---- B. weight folding ----
  // layer 2 (dst=op only): conv2 = 1/4 * [sum_r agg_r@Wl2_r + bl2_r] + 1/4 * h1op@sum(Wr2_r)
  pack_wt<<<1024, 256, 0, stream>>>(Wl2, 0, -1, -1, -1, BT2_0, 512, 0, 0.25f);
  pack_wt<<<1024, 256, 0, stream>>>(Wl2, 1, -1, -1, -1, BT2_1, 512, 0, 0.25f);
  pack_wt<<<1024, 256, 0, stream>>>(Wl2, 2, -1, -1, -1, BT2_2, 512, 0, 0.25f);
  pack_wt<<<1024, 256, 0, stream>>>(Wl2, 4, -1, -1, -1, BT2_4, 512, 0, 0.25f);
  pack_wt<<<1024, 256, 0, stream>>>(Wr2, 0, 1, 2, 4, BT2rt, 512, 0, 0.25f);
  vec_foldbias<<<2, 256, 0, stream>>>(bl2, 0, 1, 2, 4, 0.25f, nullptr, nullptr, -1, -1, -1, -1, 0.f, b2vec);
  // layer 1 folded into raw-feature space. Zero BT1 pads first.
  hipMemsetAsync(BT1op, 0, 65536 + 65536 + 131072 + 65536, stream);
  // op: K=64 : [0:2 tab|2 ind|3:7 pred|7 ind|8:40 col|40 ind|41:45 op|45 ind|46:50 root|pad]
  fold_bt<<<4, 256, 0, stream>>>(W_tab, 2, Wl1, 0, -1, -1, -1, 0.25f, BT1op, 64, 0);
  fold_bt<<<2, 256, 0, stream>>>(b_tab, 1, Wl1, 0, -1, -1, -1, 0.25f, BT1op, 64, 2);
  fold_bt<<<8, 256, 0, stream>>>(W_pred, 4, Wl1, 1, -1, -1, -1, 0.25f, BT1op, 64, 3);
  fold_bt<<<2, 256, 0, stream>>>(b_pred, 1, Wl1, 1, -1, -1, -1, 0.25f, BT1op, 64, 7);
  fold_bt<<<64, 256, 0, stream>>>(W_col, 32, Wl1, 2, -1, -1, -1, 0.25f, BT1op, 64, 8);
  fold_bt<<<2, 256, 0, stream>>>(b_col, 1, Wl1, 2, -1, -1, -1, 0.25f, BT1op, 64, 40);
  fold_bt<<<8, 256, 0, stream>>>(W_op, 4, Wl1, 4, -1, -1, -1, 0.25f, BT1op, 64, 41);
  fold_bt<<<2, 256, 0, stream>>>(b_op, 1, Wl1, 4, -1, -1, -1, 0.25f, BT1op, 64, 45);
  fold_bt<<<8, 256, 0, stream>>>(W_op, 4, Wr1, 0, 1, 2, 4, 0.25f, BT1op, 64, 46);
  vec_foldbias<<<2, 256, 0, stream>>>(bl1, 0, 1, 2, 4, 0.25f, b_op, Wr1, 0, 1, 2, 4, 0.25f, b1op);
  // tab: K=64 : [0:2 agg(rel5)|2 ind|3:5 root|pad]
  fold_bt<<<4, 256, 0, stream>>>(W_tab, 2, Wl1, 5, -1, -1, -1, 1.f, BT1tab, 64, 0);
  fold_bt<<<2, 256, 0, stream>>>(b_tab, 1, Wl1, 5, -1, -1, -1, 1.f, BT1tab, 64, 2);
  fold_bt<<<4, 256, 0, stream>>>(W_tab, 2, Wr1, 5, -1, -1, -1, 1.f, BT1tab, 64, 3);
  vec_foldbias<<<2, 256, 0, stream>>>(bl1, 5, -1, -1, -1, 1.f, b_tab, Wr1, 5, -1, -1, -1, 1.f, b1tab);
  // col: K=128 : [0:32 agg(rel6)|32 ind|33:65 root|pad]
  fold_bt<<<64, 256, 0, stream>>>(W_col, 32, Wl1, 6, -1, -1, -1, 1.f, BT1col, 128, 0);
  fold_bt<<<2, 256, 0, stream>>>(b_col, 1, Wl1, 6, -1, -1, -1, 1.f, BT1col, 128, 32);
  fold_bt<<<64, 256, 0, stream>>>(W_col, 32, Wr1, 6, -1, -1, -1, 1.f, BT1col, 128, 33);
  vec_foldbias<<<2, 256, 0, stream>>>(bl1, 6, -1, -1, -1, 1.f, b_col, Wr1, 6, -1, -1, -1, 1.f, b1col);
  // pred: K=64 : [0:32 agg(rel3, src=col)|32 ind|33:37 root|pad]
  fold_bt<<<64, 256, 0, stream>>>(W_col, 32, Wl1, 3, -1, -1, -1, 1.f, BT1pr, 64, 0);
  fold_bt<<<2, 256, 0, stream>>>(b_col, 1, Wl1, 3, -1, -1, -1, 1.f, BT1pr, 64, 32);
  fold_bt<<<8, 256, 0, stream>>>(W_pred, 4, Wr1, 3, -1, -1, -1, 1.f, BT1pr, 64, 33);
  vec_foldbias<<<2, 256, 0, stream>>>(bl1, 3, -1, -1, -1, 1.f, b_pred, Wr1, 3, -1, -1, -1, 1.f, b1pr);

  // ---- C. init acc with layer-2 bias ----
  bcast_k<<<32768, 256, 0, stream>>>(acc, b2vec, NOP);

  // helper: filtered CSR build for relation rel with src in [s0,s1)
  auto build_filt = [&](int rel, int s0, int s1) {
    hipMemsetAsync(curF, 0, 131073ull * 4, stream);
    hist_range<<<(EREL[rel] + 255) / 256, 256, 0, stream>>>(DST[rel], SRC[rel], EREL[rel], curF, s0, s1);
    scan1_k<<<129, 256, 0, stream>>>(curF, offsF, part, 131073);
    scan2_k<<<1, 1024, 0, stream>>>(part, 129);
    scan3_k<<<513, 256, 0, stream>>>(offsF, curF, part, 131073);
    fill_range<<<(EREL[rel] + 255) / 256, 256, 0, stream>>>(SRC[rel], DST[rel], EREL[rel], curF, esrcF, s0, s1);
  };
  // helper: 4x agg-chunk + accumulate-GEMM over all op dst rows
  auto rel_pass = [&](const int* oF, const int* oS, const int* eF, const u16* bt) {
    for (int c = 0; c < 4; ++c) {
      int c0 = c * 32768;
      seg_gather<<<8192, 256, 0, stream>>>(oF + c0, oS + c0, eF, hsrc, agg, 32768);
      gemm_k<false, true><<<dim3(256, 4), 256, 0, stream>>>(agg, 512, bt, nullptr,
                                                            acc + (size_t)c0 * 512, 32768);
    }
  };

  // ---- D. relation 0: tab -> op ----
  hipMemsetAsync(A1, 0, 32768ull * 64 * 2, stream);
  raw_agg<<<1024, 256, 0, stream>>>(offsFul + CSRB[5], esrcFul, x_tab, 2, A1, 64, 0, 2, 32768);
  a1_root<<<256, 256, 0, stream>>>(x_tab, 0, A1, 64, 3, 32768, 1);
  gemm_k<true, false><<<dim3(256, 4), 256, 0, stream>>>(A1, 64, BT1tab, b1tab, hsrc, 32768);
  ln_rows<false><<<8192, 256, 0, stream>>>(hsrc, g1, be1, 32768);
  rel_pass(offsFul + CSRB[0], offsFul + CSRB[0], esrcFul, BT2_0);

  // ---- E. relation 1: pred -> op ----
  hipMemsetAsync(A1, 0, 65536ull * 64 * 2, stream);
  raw_agg<<<2048, 256, 0, stream>>>(offsFul + CSRB[3], esrcFul, x_col, 32, A1, 64, 0, 32, 65536);
  a1_root<<<1024, 256, 0, stream>>>(x_pred, 0, A1, 64, 33, 65536, 2);
  gemm_k<true, false><<<dim3(512, 4), 256, 0, stream>>>(A1, 64, BT1pr, b1pr, hsrc, 65536);
  ln_rows<false><<<16384, 256, 0, stream>>>(hsrc, g1, be1, 65536);
  rel_pass(offsFul + CSRB[1], offsFul + CSRB[1], esrcFul, BT2_1);

  // ---- F. relation 2: col -> op (col recomputed in halves) ----
  for (int h = 0; h < 2; ++h) {
    int s0 = h * 65536, s1 = s0 + 65536;
    hipMemsetAsync(A1, 0, 65536ull * 128 * 2, stream);
    raw_agg<<<2048, 256, 0, stream>>>(offsFul + CSRB[6] + s0, esrcFul, x_col, 32, A1, 128, 0, 32, 65536);
    a1_root<<<8192, 256, 0, stream>>>(x_col, s0, A1, 128, 33, 65536, 5);
    gemm_k<true, false><<<dim3(512, 4), 256, 0, stream>>>(A1, 128, BT1col, b1col, hsrc, 65536);
    ln_rows<false><<<16384, 256, 0, stream>>>(hsrc, g1, be1, 65536);
    build_filt(2, s0, s1);
    rel_pass(offsF, offsFul + CSRB[2], esrcF, BT2_2);
  }

  // ---- G. op halves: root GEMM + relation 4 (op -> op) ----
  for (int h = 0; h < 2; ++h) {
    int s0 = h * 65536, s1 = s0 + 65536;
    hipMemsetAsync(A1, 0, 65536ull * 64 * 2, stream);
    raw_agg<<<2048, 256, 0, stream>>>(offsFul + CSRB[0] + s0, esrcFul, x_tab, 2, A1, 64, 0, 2, 65536);
    raw_agg<<<2048, 256, 0, stream>>>(offsFul + CSRB[1] + s0, esrcFul, x_pred, 4, A1, 64, 3, 7, 65536);
    raw_agg<<<2048, 256, 0, stream>>>(offsFul + CSRB[2] + s0, esrcFul, x_col, 32, A1, 64, 8, 40, 65536);
    raw_agg<<<2048, 256, 0, stream>>>(offsFul + CSRB[4] + s0, esrcFul, x_op, 4, A1, 64, 41, 45, 65536);
    a1_root<<<1024, 256, 0, stream>>>(x_op, s0, A1, 64, 46, 65536, 2);
    gemm_k<true, false><<<dim3(512, 4), 256, 0, stream>>>(A1, 64, BT1op, b1op, hsrc, 65536);
    ln_rows<false><<<16384, 256, 0, stream>>>(hsrc, g1, be1, 65536);
    // root: acc[s0..s1) += h1op_half @ BT2rt
    gemm_k<false, true><<<dim3(512, 4), 256, 0, stream>>>(hsrc, 512, BT2rt, nullptr,
                                                          acc + (size_t)s0 * 512, 65536);
    build_filt(4, s0, s1);
    rel_pass(offsF, offsFul + CSRB[4], esrcF, BT2_4);
  }

  // ---- H. ELU + LN2 in place, pool, output ----
  ln_rows<true><<<32768, 256, 0, stream>>>(acc, g2, be2, NOP);
  hipMemsetAsync(pooled, 0, 64 * 512 * 4, stream);
  pool1<<<512, 256, 0, stream>>>(acc, batch, NOP, pooled, cnts);
  pool2<<<64, 64, 0, stream>>>(pooled, cnts, Wout, bout, out);
}

// Round 4
// 2966.272 us; speedup vs baseline: 1.5532x; 1.5532x over previous
//
#include <hip/hip_runtime.h>
#include <hip/hip_bf16.h>

typedef unsigned short u16;
typedef __attribute__((ext_vector_type(8))) short bf16x8;
typedef __attribute__((ext_vector_type(4))) float f32x4;

typedef __attribute__((address_space(1))) const void gv_t;  // global
typedef __attribute__((address_space(3))) void lv_t;        // LDS

#define DEVINL __device__ __forceinline__

DEVINL float bf2f(u16 s) { union { unsigned u; float f; } v; v.u = ((unsigned)s) << 16; return v.f; }
DEVINL u16 f2bf(float f) {
  union { float f; unsigned u; } v; v.f = f;
  return (u16)((v.u + 0x7FFFu + ((v.u >> 16) & 1u)) >> 16);
}

// ---- ws probe (reports ws_size via absmax when workspace too small) ----
__global__ void probe_k(float* __restrict__ out, float v) { out[threadIdx.x] = v; }

// ---- BT[n*dstK + koff + k] = bf16(scale * sum_r W[(r*512+k)*512+n]) ----
__global__ void pack_wt(const float* __restrict__ W, int r0, int r1, int r2, int r3,
                        u16* __restrict__ dst, int dstK, int koff, float scale) {
  int idx = blockIdx.x * 256 + threadIdx.x;
  if (idx >= 512 * 512) return;
  int k = idx >> 9, n = idx & 511;
  float v = W[((size_t)r0 * 512 + k) * 512 + n];
  if (r1 >= 0) v += W[((size_t)r1 * 512 + k) * 512 + n];
  if (r2 >= 0) v += W[((size_t)r2 * 512 + k) * 512 + n];
  if (r3 >= 0) v += W[((size_t)r3 * 512 + k) * 512 + n];
  dst[(size_t)n * dstK + koff + k] = f2bf(v * scale);
}

// ---- parallel fold: BT[n*K+koff+f] = bf16(scale * sum_k A[f*512+k]*sum_r W[..k..n])
// grid = F*8 blocks, block 256 = 64 n x 4 k-groups (128 k each), LDS reduce.
__global__ void fold_bt2(const float* __restrict__ A, int F, const float* __restrict__ W,
                         int r0, int r1, int r2, int r3, float scale,
                         u16* __restrict__ BT, int K, int koff) {
  __shared__ float red[256];
  int f = blockIdx.x >> 3;
  int n = (blockIdx.x & 7) * 64 + (threadIdx.x & 63);
  int kg = threadIdx.x >> 6;  // 0..3
  float a = 0.f;
#pragma unroll 4
  for (int k = kg * 128; k < kg * 128 + 128; ++k) {
    float w = W[((size_t)r0 * 512 + k) * 512 + n];
    if (r1 >= 0) w += W[((size_t)r1 * 512 + k) * 512 + n];
    if (r2 >= 0) w += W[((size_t)r2 * 512 + k) * 512 + n];
    if (r3 >= 0) w += W[((size_t)r3 * 512 + k) * 512 + n];
    a += A[(size_t)f * 512 + k] * w;
  }
  red[threadIdx.x] = a;
  __syncthreads();
  if (kg == 0) {
    a = red[threadIdx.x] + red[threadIdx.x + 64] + red[threadIdx.x + 128] + red[threadIdx.x + 192];
    BT[(size_t)n * K + koff + f] = f2bf(a * scale);
  }
}

// ---- out[n] = blscale*sum(bl_i[n]) + bscale*sum_k bvec[k]*sum_r W[..k..n]
// grid = 16 blocks, block 256 = 32 n x 8 k-groups (64 k each).
__global__ void vec_foldbias2(const float* __restrict__ bl, int i0, int i1, int i2, int i3,
                              float blscale, const float* __restrict__ bvec,
                              const float* __restrict__ W, int j0, int j1, int j2, int j3,
                              float bscale, float* __restrict__ out) {
  __shared__ float red[256];
  int n = blockIdx.x * 32 + (threadIdx.x & 31);
  int kg = threadIdx.x >> 5;  // 0..7
  float a = 0.f;
  if (bvec) {
#pragma unroll 4
    for (int k = kg * 64; k < kg * 64 + 64; ++k) {
      float w = W[((size_t)j0 * 512 + k) * 512 + n];
      if (j1 >= 0) w += W[((size_t)j1 * 512 + k) * 512 + n];
      if (j2 >= 0) w += W[((size_t)j2 * 512 + k) * 512 + n];
      if (j3 >= 0) w += W[((size_t)j3 * 512 + k) * 512 + n];
      a += bvec[k] * w;
    }
  }
  red[threadIdx.x] = a;
  __syncthreads();
  if (kg == 0) {
    float v = 0.f;
#pragma unroll
    for (int q = 0; q < 8; ++q) v += red[(threadIdx.x & 31) + q * 32];
    v *= bscale;
    if (bl) {
      float b = bl[i0 * 512 + n];
      if (i1 >= 0) b += bl[i1 * 512 + n];
      if (i2 >= 0) b += bl[i2 * 512 + n];
      if (i3 >= 0) b += bl[i3 * 512 + n];
      v += blscale * b;
    }
    out[n] = v;
  }
}

// ---- CSR build ----
__global__ void hist_k(const int* __restrict__ dst, int nE, int* __restrict__ cnt) {
  int i = blockIdx.x * 256 + threadIdx.x;
  if (i < nE) atomicAdd(&cnt[dst[i]], 1);
}

__global__ void hist_range(const int* __restrict__ dst, const int* __restrict__ src, int nE,
                           int* __restrict__ cnt, int s0, int s1) {
  int i = blockIdx.x * 256 + threadIdx.x;
  if (i < nE) {
    int s = src[i];
    if (s >= s0 && s < s1) atomicAdd(&cnt[dst[i]], 1);
  }
}

__global__ void scan1_k(const int* __restrict__ in, int* __restrict__ out,
                        int* __restrict__ part, int n) {
  __shared__ int s[256];
  int t = threadIdx.x;
  int base = blockIdx.x * 1024 + t * 4;
  int x0 = 0, x1 = 0, x2 = 0, x3 = 0;
  if (base < n) x0 = in[base];
  if (base + 1 < n) x1 = in[base + 1];
  if (base + 2 < n) x2 = in[base + 2];
  if (base + 3 < n) x3 = in[base + 3];
  int tsum = x0 + x1 + x2 + x3;
  s[t] = tsum;
  __syncthreads();
  for (int off = 1; off < 256; off <<= 1) {
    int v = (t >= off) ? s[t - off] : 0;
    __syncthreads();
    s[t] += v;
    __syncthreads();
  }
  int excl = s[t] - tsum;
  if (base < n) out[base] = excl;
  if (base + 1 < n) out[base + 1] = excl + x0;
  if (base + 2 < n) out[base + 2] = excl + x0 + x1;
  if (base + 3 < n) out[base + 3] = excl + x0 + x1 + x2;
  if (t == 255) part[blockIdx.x] = s[255];
}

__global__ void scan2_k(int* __restrict__ part, int nb) {
  __shared__ int s[1024];
  int t = threadIdx.x;
  int orig = (t < nb) ? part[t] : 0;
  s[t] = orig;
  __syncthreads();
  for (int off = 1; off < 1024; off <<= 1) {
    int v = (t >= off) ? s[t - off] : 0;
    __syncthreads();
    s[t] += v;
    __syncthreads();
  }
  if (t < nb) part[t] = s[t] - orig;
}

__global__ void scan3_k(int* __restrict__ out, int* __restrict__ cursor,
                        const int* __restrict__ part, int n) {
  int i = blockIdx.x * 256 + threadIdx.x;
  if (i < n) {
    int v = out[i] + part[i >> 10];
    out[i] = v;
    cursor[i] = v;
  }
}

__global__ void fill_range(const int* __restrict__ src, const int* __restrict__ dst, int nE,
                           int* __restrict__ cursor, int* __restrict__ esrc, int s0, int s1) {
  int i = blockIdx.x * 256 + threadIdx.x;
  if (i >= nE) return;
  int s = src[i];
  if (s >= s0 && s < s1) {
    int pos = atomicAdd(&cursor[dst[i]], 1);
    esrc[pos] = s - s0;
  }
}

// ---- raw-feature segment mean + indicator (8 threads per dst row) ----
__global__ void raw_agg(const int* __restrict__ offs, const int* __restrict__ esrc,
                        const float* __restrict__ x, int F, u16* __restrict__ A1,
                        int K, int colOff, int indCol, int nd) {
  int row = blockIdx.x * 32 + (threadIdx.x >> 3);
  if (row >= nd) return;
  int j = threadIdx.x & 7;
  int e0 = offs[row], e1 = offs[row + 1];
  float acc[4] = {0.f, 0.f, 0.f, 0.f};
  for (int e = e0; e < e1; ++e) {
    int s = esrc[e];
#pragma unroll
    for (int u = 0; u < 4; ++u) {
      int f = j + u * 8;
      if (f < F) acc[u] += x[(size_t)s * F + f];
    }
  }
  float inv = (e1 > e0) ? 1.f / (float)(e1 - e0) : 0.f;
#pragma unroll
  for (int u = 0; u < 4; ++u) {
    int f = j + u * 8;
    if (f < F) A1[(size_t)row * K + colOff + f] = f2bf(acc[u] * inv);
  }
  if (j == 0) A1[(size_t)row * K + indCol] = f2bf((e1 > e0) ? 1.f : 0.f);
}

// ---- copy root raw features into A1 ----
__global__ void a1_root(const float* __restrict__ x, int rowBase, u16* __restrict__ A1,
                        int K, int rootOff, int nd, int lf) {
  int idx = blockIdx.x * 256 + threadIdx.x;
  int i = idx >> lf, f = idx & ((1 << lf) - 1);
  if (i >= nd) return;
  A1[(size_t)i * K + rootOff + f] = f2bf(x[(((size_t)(rowBase + i)) << lf) + f]);
}

// ---- gather partial segment-sums scaled by 1/full-count (wave per dst row) ----
__global__ void seg_gather(const int* __restrict__ offsF, const int* __restrict__ offsS,
                           const int* __restrict__ esrcF, const u16* __restrict__ hsrc,
                           u16* __restrict__ agg, int nd) {
  int w = blockIdx.x * 4 + (threadIdx.x >> 6);
  if (w >= nd) return;
  int l = threadIdx.x & 63;
  int e0 = offsF[w], e1 = offsF[w + 1];
  int c0 = offsS[w], c1 = offsS[w + 1];
  float inv = (c1 > c0) ? 1.f / (float)(c1 - c0) : 0.f;
  float acc[8] = {0.f, 0.f, 0.f, 0.f, 0.f, 0.f, 0.f, 0.f};
  for (int e = e0; e < e1; ++e) {
    int s = esrcF[e];
    bf16x8 v = *(const bf16x8*)&hsrc[(size_t)s * 512 + l * 8];
#pragma unroll
    for (int j = 0; j < 8; ++j) acc[j] += bf2f((u16)v[j]);
  }
  bf16x8 r;
#pragma unroll
  for (int j = 0; j < 8; ++j) r[j] = (short)f2bf(acc[j] * inv);
  *(bf16x8*)&agg[(size_t)w * 512 + l * 8] = r;
}

// ---- MFMA GEMM: C[M][512] (+)= op(A[M][K] @ BT[512][K]^T + bias), bf16 ----
// T2 XOR-swizzled LDS (rule #21: linear gload_lds dest + pre-swizzled global src + swizzled read)
template <bool ELU, bool ACC>
__global__ __launch_bounds__(256) void gemm_k(
    const u16* __restrict__ A, int K, const u16* __restrict__ BT,
    const float* __restrict__ bias, u16* __restrict__ C, int M) {
  __shared__ u16 As[128 * 64];
  __shared__ u16 Bs[128 * 64];
  int tid = threadIdx.x;
  int wid = tid >> 6, lane = tid & 63;
  int wm = wid >> 1, wn = wid & 1;
  int bm = blockIdx.x * 128, bn = blockIdx.y * 128;
  int r16 = lane & 15, hi4 = lane >> 4;
  int srow = tid >> 3;
  int scol = ((tid & 7) ^ (srow & 7)) * 8;  // pre-swizzled source column group
  int sw = r16 & 7;                          // read-side XOR key
  f32x4 acc[4][4];
#pragma unroll
  for (int i = 0; i < 4; ++i)
#pragma unroll
    for (int j = 0; j < 4; ++j) acc[i][j] = (f32x4){0.f, 0.f, 0.f, 0.f};

  for (int k0 = 0; k0 < K; k0 += 64) {
    __syncthreads();
#pragma unroll
    for (int i = 0; i < 4; ++i) {
      const u16* ga = A + (size_t)(bm + i * 32 + srow) * K + k0 + scol;
      const u16* gb = BT + (size_t)(bn + i * 32 + srow) * K + k0 + scol;
      __builtin_amdgcn_global_load_lds((gv_t*)ga, (lv_t*)(As + i * 2048 + wid * 512), 16, 0, 0);
      __builtin_amdgcn_global_load_lds((gv_t*)gb, (lv_t*)(Bs + i * 2048 + wid * 512), 16, 0, 0);
    }
    __syncthreads();
#pragma unroll
    for (int kk = 0; kk < 64; kk += 32) {
      bf16x8 af[4], bfr[4];
#pragma unroll
      for (int f = 0; f < 4; ++f) {
        int grp = (kk >> 3) + hi4;
        af[f]  = *(const bf16x8*)&As[(wm * 64 + f * 16 + r16) * 64 + ((grp ^ sw) << 3)];
        bfr[f] = *(const bf16x8*)&Bs[(wn * 64 + f * 16 + r16) * 64 + ((grp ^ sw) << 3)];
      }
#pragma unroll
      for (int mf = 0; mf < 4; ++mf)
#pragma unroll
        for (int nf = 0; nf < 4; ++nf)
          acc[mf][nf] = __builtin_amdgcn_mfma_f32_16x16x32_bf16(af[mf], bfr[nf], acc[mf][nf], 0, 0, 0);
    }
  }
#pragma unroll
  for (int mf = 0; mf < 4; ++mf) {
#pragma unroll
    for (int nf = 0; nf < 4; ++nf) {
      int c = bn + wn * 64 + nf * 16 + r16;
      float bv = bias ? bias[c] : 0.f;
#pragma unroll
      for (int j = 0; j < 4; ++j) {
        int r = bm + wm * 64 + mf * 16 + hi4 * 4 + j;
        float v = acc[mf][nf][j] + bv;
        if (ACC) v += bf2f(C[(size_t)r * 512 + c]);
        if (ELU) v = v > 0.f ? v : expm1f(v);
        C[(size_t)r * 512 + c] = f2bf(v);
      }
    }
  }
}

// ---- acc init: broadcast bias vector ----
__global__ void bcast_k(u16* __restrict__ acc, const float* __restrict__ bv, int rows) {
  int idx = blockIdx.x * 256 + threadIdx.x;
  int row = idx >> 6, c8 = (idx & 63) * 8;
  if (row >= rows) return;
  bf16x8 r;
#pragma unroll
  for (int j = 0; j < 8; ++j) r[j] = (short)f2bf(bv[c8 + j]);
  *(bf16x8*)&acc[(size_t)row * 512 + c8] = r;
}

// ---- LayerNorm in place (optional ELU first); wave per row ----
template <bool ELU>
__global__ void ln_rows(u16* __restrict__ H, const float* __restrict__ g,
                        const float* __restrict__ be, int rows) {
  int w = blockIdx.x * 4 + (threadIdx.x >> 6);
  if (w >= rows) return;
  int l = threadIdx.x & 63;
  u16* p = H + (size_t)w * 512 + l * 8;
  bf16x8 v = *(const bf16x8*)p;
  float x[8];
  float s = 0.f;
#pragma unroll
  for (int j = 0; j < 8; ++j) {
    x[j] = bf2f((u16)v[j]);
    if (ELU) x[j] = x[j] > 0.f ? x[j] : expm1f(x[j]);
    s += x[j];
  }
#pragma unroll
  for (int m = 1; m < 64; m <<= 1) s += __shfl_xor(s, m, 64);
  float mean = s * (1.f / 512.f);
  float q = 0.f;
#pragma unroll
  for (int j = 0; j < 8; ++j) { float d = x[j] - mean; q += d * d; }
#pragma unroll
  for (int m = 1; m < 64; m <<= 1) q += __shfl_xor(q, m, 64);
  float rsd = rsqrtf(q * (1.f / 512.f) + 1e-5f);
  bf16x8 r;
#pragma unroll
  for (int j = 0; j < 8; ++j) {
    int c = l * 8 + j;
    r[j] = (short)f2bf((x[j] - mean) * rsd * g[c] + be[c]);
  }
  *(bf16x8*)p = r;
}

// ---- pooling ----
DEVINL int lowb(const int* a, int n, int v) {
  int lo = 0, hi = n;
  while (lo < hi) { int m = (lo + hi) >> 1; if (a[m] < v) lo = m + 1; else hi = m; }
  return lo;
}

__global__ void pool1(const u16* __restrict__ H, const int* __restrict__ batch, int nOp,
                      float* __restrict__ pooled, int* __restrict__ cnts) {
  int g = blockIdx.x >> 3, part = blockIdx.x & 7;
  int lo = lowb(batch, nOp, g), hi = lowb(batch, nOp, g + 1);
  if (part == 0 && threadIdx.x == 0) cnts[g] = hi - lo;
  int len = hi - lo;
  int chunk = (len + 7) >> 3;
  int r0 = lo + part * chunk;
  int r1 = r0 + chunk;
  if (r1 > hi) r1 = hi;
  int t = threadIdx.x;
  float a0 = 0.f, a1 = 0.f;
  for (int r = r0; r < r1; ++r) {
    a0 += bf2f(H[(size_t)r * 512 + t]);
    a1 += bf2f(H[(size_t)r * 512 + t + 256]);
  }
  atomicAdd(&pooled[g * 512 + t], a0);
  atomicAdd(&pooled[g * 512 + t + 256], a1);
}

__global__ void pool2(const float* __restrict__ pooled, const int* __restrict__ cnts,
                      const float* __restrict__ Wout, const float* __restrict__ bout,
                      float* __restrict__ out) {
  int gg = blockIdx.x;
  int l = threadIdx.x;
  float s = 0.f;
#pragma unroll
  for (int j = 0; j < 8; ++j) {
    int c = l * 8 + j;
    s += pooled[gg * 512 + c] * Wout[c];
  }
#pragma unroll
  for (int m = 1; m < 64; m <<= 1) s += __shfl_xor(s, m, 64);
  if (l == 0) {
    int c = cnts[gg];
    if (c < 1) c = 1;
    out[gg] = s / (float)c + bout[0];
  }
}

extern "C" void kernel_launch(void* const* d_in, const int* in_sizes, int n_in,
                              void* d_out, int out_size, void* d_ws, size_t ws_size,
                              hipStream_t stream) {
  (void)in_sizes; (void)n_in; (void)out_size;
  // inputs: node feats 0=op,1=tab,2=col,3=pred
  const float* x_op   = (const float*)d_in[0];
  const float* x_tab  = (const float*)d_in[1];
  const float* x_col  = (const float*)d_in[2];
  const float* x_pred = (const float*)d_in[3];
  const float* W_op = (const float*)d_in[4],  *b_op = (const float*)d_in[5];
  const float* W_tab = (const float*)d_in[6], *b_tab = (const float*)d_in[7];
  const float* W_col = (const float*)d_in[8], *b_col = (const float*)d_in[9];
  const float* W_pred = (const float*)d_in[10], *b_pred = (const float*)d_in[11];
  const float* Wl1 = (const float*)d_in[12];
  const float* bl1 = (const float*)d_in[13];
  const float* Wr1 = (const float*)d_in[14];
  const float* Wl2 = (const float*)d_in[15];
  const float* bl2 = (const float*)d_in[16];
  const float* Wr2 = (const float*)d_in[17];
  const float* g1  = (const float*)d_in[18];
  const float* be1 = (const float*)d_in[19];
  const float* g2  = (const float*)d_in[20];
  const float* be2 = (const float*)d_in[21];
  const float* Wout = (const float*)d_in[22];
  const float* bout = (const float*)d_in[23];
  const int* SRC[7], *DST[7];
  for (int r = 0; r < 7; ++r) { SRC[r] = (const int*)d_in[24 + 2 * r]; DST[r] = (const int*)d_in[25 + 2 * r]; }
  const int* batch = (const int*)d_in[38];
  float* out = (float*)d_out;

  const int EREL[7] = {262144, 262144, 262144, 262144, 262144, 32768, 131072};
  const int CSRB[7] = {0, 131072, 262144, 393216, 458752, 589824, 622592};
  const int TOT = 753664;
  const int NOP = 131072;

  // ---- workspace layout (256 MiB budget) ----
  char* ws = (char*)d_ws;
  u16* acc    = (u16*)ws;                            // 134,217,728 : conv2_op accumulator (bf16)
  u16* hsrc   = (u16*)(ws + 134217728ull);           //  67,108,864 : recomputed layer-1 h chunk
  u16* agg    = (u16*)(ws + 201326592ull);           //  33,554,432 : [32768x512] bf16 agg chunk
  int* curFul = (int*)(ws + 201326592ull);           //   (overlay in agg: CSR-build cursor)
  u16* A1     = (u16*)(ws + 234881024ull);           //  16,777,216 : [65536x128] bf16 features
  int* offsFul= (int*)(ws + 251658240ull);           //   3,014,912 : (TOT+1) offsets
  int* esrcFul= (int*)(ws + 254673152ull);           //   5,898,240
  int* offsF  = (int*)(ws + 260571392ull);           //     524,544 : filtered CSR (131073)
  int* curF   = (int*)(ws + 261095936ull);           //     524,544
  int* esrcF  = (int*)(ws + 261620480ull);           //   1,048,576
  u16* BT2_0  = (u16*)(ws + 262669056ull);           //   5x524,288 : layer-2 weights [512x512]
  u16* BT2_1  = BT2_0 + 262144;
  u16* BT2_2  = BT2_1 + 262144;
  u16* BT2_4  = BT2_2 + 262144;
  u16* BT2rt  = BT2_4 + 262144;
  u16* BT1op  = (u16*)(ws + 265290496ull);           //      65,536 : [512x64]
  u16* BT1tab = (u16*)(ws + 265356032ull);           //      65,536
  u16* BT1col = (u16*)(ws + 265421568ull);           //     131,072 : [512x128]
  u16* BT1pr  = (u16*)(ws + 265552640ull);           //      65,536
  float* b1op = (float*)(ws + 265618176ull);         //   5x2048 bias vecs
  float* b1tab = b1op + 512, *b1col = b1op + 1024, *b1pr = b1op + 1536, *b2vec = b1op + 2048;
  float* pooled = (float*)(ws + 265628416ull);       //     131,072
  int* cnts     = (int*)(ws + 265759488ull);         //         256
  int* part     = (int*)(ws + 265759744ull);         //       4,096
  const size_t WS_NEED = 265763840ull;
  if (ws_size < WS_NEED) { probe_k<<<1, 64, 0, stream>>>(out, (float)ws_size); return; }

  // ---- A. full CSR for all 7 relations ----
  hipMemsetAsync(curFul, 0, (size_t)(TOT + 1) * 4, stream);
  for (int r = 0; r < 7; ++r)
    hist_k<<<(EREL[r] + 255) / 256, 256, 0, stream>>>(DST[r], EREL[r], curFul + CSRB[r]);
  scan1_k<<<737, 256, 0, stream>>>(curFul, offsFul, part, TOT + 1);
  scan2_k<<<1, 1024, 0, stream>>>(part, 737);
  scan3_k<<<2945, 256, 0, stream>>>(offsFul, curFul, part, TOT + 1);
  for (int r = 0; r < 7; ++r)
    fill_range<<<(EREL[r] + 255) / 256, 256, 0, stream>>>(SRC[r], DST[r], EREL[r],
                                                          curFul + CSRB[r], esrcFul, 0, 1 << 30);

  // ---- B. weight folding ----
  // layer 2 (dst=op only): conv2 = 1/4 * [sum_r agg_r@Wl2_r + bl2_r] + 1/4 * h1op@sum(Wr2_r)
  pack_wt<<<1024, 256, 0, stream>>>(Wl2, 0, -1, -1, -1, BT2_0, 512, 0, 0.25f);
  pack_wt<<<1024, 256, 0, stream>>>(Wl2, 1, -1, -1, -1, BT2_1, 512, 0, 0.25f);
  pack_wt<<<1024, 256, 0, stream>>>(Wl2, 2, -1, -1, -1, BT2_2, 512, 0, 0.25f);
  pack_wt<<<1024, 256, 0, stream>>>(Wl2, 4, -1, -1, -1, BT2_4, 512, 0, 0.25f);
  pack_wt<<<1024, 256, 0, stream>>>(Wr2, 0, 1, 2, 4, BT2rt, 512, 0, 0.25f);
  vec_foldbias2<<<16, 256, 0, stream>>>(bl2, 0, 1, 2, 4, 0.25f, nullptr, nullptr, -1, -1, -1, -1, 0.f, b2vec);
  // layer 1 folded into raw-feature space. Zero BT1 pads first.
  hipMemsetAsync(BT1op, 0, 65536 + 65536 + 131072 + 65536, stream);
  // op: K=64 : [0:2 tab|2 ind|3:7 pred|7 ind|8:40 col|40 ind|41:45 op|45 ind|46:50 root|pad]
  fold_bt2<<<16, 256, 0, stream>>>(W_tab, 2, Wl1, 0, -1, -1, -1, 0.25f, BT1op, 64, 0);
  fold_bt2<<<8, 256, 0, stream>>>(b_tab, 1, Wl1, 0, -1, -1, -1, 0.25f, BT1op, 64, 2);
  fold_bt2<<<32, 256, 0, stream>>>(W_pred, 4, Wl1, 1, -1, -1, -1, 0.25f, BT1op, 64, 3);
  fold_bt2<<<8, 256, 0, stream>>>(b_pred, 1, Wl1, 1, -1, -1, -1, 0.25f, BT1op, 64, 7);
  fold_bt2<<<256, 256, 0, stream>>>(W_col, 32, Wl1, 2, -1, -1, -1, 0.25f, BT1op, 64, 8);
  fold_bt2<<<8, 256, 0, stream>>>(b_col, 1, Wl1, 2, -1, -1, -1, 0.25f, BT1op, 64, 40);
  fold_bt2<<<32, 256, 0, stream>>>(W_op, 4, Wl1, 4, -1, -1, -1, 0.25f, BT1op, 64, 41);
  fold_bt2<<<8, 256, 0, stream>>>(b_op, 1, Wl1, 4, -1, -1, -1, 0.25f, BT1op, 64, 45);
  fold_bt2<<<32, 256, 0, stream>>>(W_op, 4, Wr1, 0, 1, 2, 4, 0.25f, BT1op, 64, 46);
  vec_foldbias2<<<16, 256, 0, stream>>>(bl1, 0, 1, 2, 4, 0.25f, b_op, Wr1, 0, 1, 2, 4, 0.25f, b1op);
  // tab: K=64 : [0:2 agg(rel5)|2 ind|3:5 root|pad]
  fold_bt2<<<16, 256, 0, stream>>>(W_tab, 2, Wl1, 5, -1, -1, -1, 1.f, BT1tab, 64, 0);
  fold_bt2<<<8, 256, 0, stream>>>(b_tab, 1, Wl1, 5, -1, -1, -1, 1.f, BT1tab, 64, 2);
  fold_bt2<<<16, 256, 0, stream>>>(W_tab, 2, Wr1, 5, -1, -1, -1, 1.f, BT1tab, 64, 3);
  vec_foldbias2<<<16, 256, 0, stream>>>(bl1, 5, -1, -1, -1, 1.f, b_tab, Wr1, 5, -1, -1, -1, 1.f, b1tab);
  // col: K=128 : [0:32 agg(rel6)|32 ind|33:65 root|pad]
  fold_bt2<<<256, 256, 0, stream>>>(W_col, 32, Wl1, 6, -1, -1, -1, 1.f, BT1col, 128, 0);
  fold_bt2<<<8, 256, 0, stream>>>(b_col, 1, Wl1, 6, -1, -1, -1, 1.f, BT1col, 128, 32);
  fold_bt2<<<256, 256, 0, stream>>>(W_col, 32, Wr1, 6, -1, -1, -1, 1.f, BT1col, 128, 33);
  vec_foldbias2<<<16, 256, 0, stream>>>(bl1, 6, -1, -1, -1, 1.f, b_col, Wr1, 6, -1, -1, -1, 1.f, b1col);
  // pred: K=64 : [0:32 agg(rel3, src=col)|32 ind|33:37 root|pad]
  fold_bt2<<<256, 256, 0, stream>>>(W_col, 32, Wl1, 3, -1, -1, -1, 1.f, BT1pr, 64, 0);
  fold_bt2<<<8, 256, 0, stream>>>(b_col, 1, Wl1, 3, -1, -1, -1, 1.f, BT1pr, 64, 32);
  fold_bt2<<<32, 256, 0, stream>>>(W_pred, 4, Wr1, 3, -1, -1, -1, 1.f, BT1pr, 64, 33);
  vec_foldbias2<<<16, 256, 0, stream>>>(bl1, 3, -1, -1, -1, 1.f, b_pred, Wr1, 3, -1, -1, -1, 1.f, b1pr);

  // ---- C. init acc with layer-2 bias ----
  bcast_k<<<32768, 256, 0, stream>>>(acc, b2vec, NOP);

  // helper: filtered CSR build for relation rel with src in [s0,s1)
  auto build_filt = [&](int rel, int s0, int s1) {
    hipMemsetAsync(curF, 0, 131073ull * 4, stream);
    hist_range<<<(EREL[rel] + 255) / 256, 256, 0, stream>>>(DST[rel], SRC[rel], EREL[rel], curF, s0, s1);
    scan1_k<<<129, 256, 0, stream>>>(curF, offsF, part, 131073);
    scan2_k<<<1, 1024, 0, stream>>>(part, 129);
    scan3_k<<<513, 256, 0, stream>>>(offsF, curF, part, 131073);
    fill_range<<<(EREL[rel] + 255) / 256, 256, 0, stream>>>(SRC[rel], DST[rel], EREL[rel], curF, esrcF, s0, s1);
  };
  // helper: 4x agg-chunk + accumulate-GEMM over all op dst rows
  auto rel_pass = [&](const int* oF, const int* oS, const int* eF, const u16* bt) {
    for (int c = 0; c < 4; ++c) {
      int c0 = c * 32768;
      seg_gather<<<8192, 256, 0, stream>>>(oF + c0, oS + c0, eF, hsrc, agg, 32768);
      gemm_k<false, true><<<dim3(256, 4), 256, 0, stream>>>(agg, 512, bt, nullptr,
                                                            acc + (size_t)c0 * 512, 32768);
    }
  };

  // ---- D. relation 0: tab -> op ----
  hipMemsetAsync(A1, 0, 32768ull * 64 * 2, stream);
  raw_agg<<<1024, 256, 0, stream>>>(offsFul + CSRB[5], esrcFul, x_tab, 2, A1, 64, 0, 2, 32768);
  a1_root<<<256, 256, 0, stream>>>(x_tab, 0, A1, 64, 3, 32768, 1);
  gemm_k<true, false><<<dim3(256, 4), 256, 0, stream>>>(A1, 64, BT1tab, b1tab, hsrc, 32768);
  ln_rows<false><<<8192, 256, 0, stream>>>(hsrc, g1, be1, 32768);
  rel_pass(offsFul + CSRB[0], offsFul + CSRB[0], esrcFul, BT2_0);

  // ---- E. relation 1: pred -> op ----
  hipMemsetAsync(A1, 0, 65536ull * 64 * 2, stream);
  raw_agg<<<2048, 256, 0, stream>>>(offsFul + CSRB[3], esrcFul, x_col, 32, A1, 64, 0, 32, 65536);
  a1_root<<<1024, 256, 0, stream>>>(x_pred, 0, A1, 64, 33, 65536, 2);
  gemm_k<true, false><<<dim3(512, 4), 256, 0, stream>>>(A1, 64, BT1pr, b1pr, hsrc, 65536);
  ln_rows<false><<<16384, 256, 0, stream>>>(hsrc, g1, be1, 65536);
  rel_pass(offsFul + CSRB[1], offsFul + CSRB[1], esrcFul, BT2_1);

  // ---- F. relation 2: col -> op (col recomputed in halves) ----
  for (int h = 0; h < 2; ++h) {
    int s0 = h * 65536, s1 = s0 + 65536;
    hipMemsetAsync(A1, 0, 65536ull * 128 * 2, stream);
    raw_agg<<<2048, 256, 0, stream>>>(offsFul + CSRB[6] + s0, esrcFul, x_col, 32, A1, 128, 0, 32, 65536);
    a1_root<<<8192, 256, 0, stream>>>(x_col, s0, A1, 128, 33, 65536, 5);
    gemm_k<true, false><<<dim3(512, 4), 256, 0, stream>>>(A1, 128, BT1col, b1col, hsrc, 65536);
    ln_rows<false><<<16384, 256, 0, stream>>>(hsrc, g1, be1, 65536);
    build_filt(2, s0, s1);
    rel_pass(offsF, offsFul + CSRB[2], esrcF, BT2_2);
  }

  // ---- G. op halves: root GEMM + relation 4 (op -> op) ----
  for (int h = 0; h < 2; ++h) {
    int s0 = h * 65536, s1 = s0 + 65536;
    hipMemsetAsync(A1, 0, 65536ull * 64 * 2, stream);
    raw_agg<<<2048, 256, 0, stream>>>(offsFul + CSRB[0] + s0, esrcFul, x_tab, 2, A1, 64, 0, 2, 65536);
    raw_agg<<<2048, 256, 0, stream>>>(offsFul + CSRB[1] + s0, esrcFul, x_pred, 4, A1, 64, 3, 7, 65536);
    raw_agg<<<2048, 256, 0, stream>>>(offsFul + CSRB[2] + s0, esrcFul, x_col, 32, A1, 64, 8, 40, 65536);
    raw_agg<<<2048, 256, 0, stream>>>(offsFul + CSRB[4] + s0, esrcFul, x_op, 4, A1, 64, 41, 45, 65536);
    a1_root<<<1024, 256, 0, stream>>>(x_op, s0, A1, 64, 46, 65536, 2);
    gemm_k<true, false><<<dim3(512, 4), 256, 0, stream>>>(A1, 64, BT1op, b1op, hsrc, 65536);
    ln_rows<false><<<16384, 256, 0, stream>>>(hsrc, g1, be1, 65536);
    // root: acc[s0..s1) += h1op_half @ BT2rt
    gemm_k<false, true><<<dim3(512, 4), 256, 0, stream>>>(hsrc, 512, BT2rt, nullptr,
                                                          acc + (size_t)s0 * 512, 65536);
    build_filt(4, s0, s1);
    rel_pass(offsF, offsFul + CSRB[4], esrcF, BT2_4);
  }

  // ---- H. ELU + LN2 in place, pool, output ----
  ln_rows<true><<<32768, 256, 0, stream>>>(acc, g2, be2, NOP);
  hipMemsetAsync(pooled, 0, 64 * 512 * 4, stream);
  pool1<<<512, 256, 0, stream>>>(acc, batch, NOP, pooled, cnts);
  pool2<<<64, 64, 0, stream>>>(pooled, cnts, Wout, bout, out);
}

// Round 5
// 2482.727 us; speedup vs baseline: 1.8557x; 1.1948x over previous
//
#include <hip/hip_runtime.h>
#include <hip/hip_bf16.h>

typedef unsigned short u16;
typedef __attribute__((ext_vector_type(8))) short bf16x8;
typedef __attribute__((ext_vector_type(4))) float f32x4;

typedef __attribute__((address_space(1))) const void gv_t;  // global
typedef __attribute__((address_space(3))) void lv_t;        // LDS

#define DEVINL __device__ __forceinline__

DEVINL float bf2f(u16 s) { union { unsigned u; float f; } v; v.u = ((unsigned)s) << 16; return v.f; }
DEVINL u16 f2bf(float f) {
  union { float f; unsigned u; } v; v.f = f;
  return (u16)((v.u + 0x7FFFu + ((v.u >> 16) & 1u)) >> 16);
}

// ---- ws probe (reports ws_size via absmax when workspace too small) ----
__global__ void probe_k(float* __restrict__ out, float v) { out[threadIdx.x] = v; }

// ---- BT[n*dstK + koff + k] = bf16(scale * sum_r W[(r*512+k)*512+n]) ----
__global__ void pack_wt(const float* __restrict__ W, int r0, int r1, int r2, int r3,
                        u16* __restrict__ dst, int dstK, int koff, float scale) {
  int idx = blockIdx.x * 256 + threadIdx.x;
  if (idx >= 512 * 512) return;
  int k = idx >> 9, n = idx & 511;
  float v = W[((size_t)r0 * 512 + k) * 512 + n];
  if (r1 >= 0) v += W[((size_t)r1 * 512 + k) * 512 + n];
  if (r2 >= 0) v += W[((size_t)r2 * 512 + k) * 512 + n];
  if (r3 >= 0) v += W[((size_t)r3 * 512 + k) * 512 + n];
  dst[(size_t)n * dstK + koff + k] = f2bf(v * scale);
}

// ================= batched weight folding (all 18 jobs, one launch) =================
// job j, block layout: blocks [c_off[j], c_off[j+1]), rel = blk - c_off[j];
// f = rel>>3 (source feature row), nb = rel&7 (64-wide n tile), kg = tid>>6 (4 k-groups of 128)
struct FoldPtrs { const float* a[8]; const float* w[2]; u16* bt[4]; };

__constant__ int   c_off[19] = {0,16,24,56,64,320,328,360,368,400,416,424,440,696,704,960,1216,1224,1256};
__constant__ int   c_ai[18]  = {0,1,2,3,4,5,6,7,6, 0,1,0, 4,5,4, 4,5,2};
__constant__ int   c_wi[18]  = {0,0,0,0,0,0,0,0,1, 0,0,1, 0,0,1, 0,0,1};
__constant__ int   c_r0[18]  = {0,0,1,1,2,2,4,4,0, 5,5,5, 6,6,6, 3,3,3};
__constant__ float c_sc[18]  = {0.25f,0.25f,0.25f,0.25f,0.25f,0.25f,0.25f,0.25f,0.25f,
                                1.f,1.f,1.f, 1.f,1.f,1.f, 1.f,1.f,1.f};
__constant__ int   c_bt[18]  = {0,0,0,0,0,0,0,0,0, 1,1,1, 2,2,2, 3,3,3};
__constant__ int   c_K[18]   = {64,64,64,64,64,64,64,64,64, 64,64,64, 128,128,128, 64,64,64};
__constant__ int   c_ko[18]  = {0,2,3,7,8,40,41,45,46, 0,2,3, 0,32,33, 0,32,33};

__global__ __launch_bounds__(256) void fold_multi(FoldPtrs p) {
  __shared__ float red[256];
  int b = blockIdx.x;
  int j = 0;
#pragma unroll
  for (int t = 1; t < 18; ++t) j += (b >= c_off[t]);
  int rel = b - c_off[j];
  int f = rel >> 3, nb = rel & 7;
  int tid = threadIdx.x;
  int n = nb * 64 + (tid & 63);
  int kg = tid >> 6;
  const float* A = p.a[c_ai[j]] + (size_t)f * 512;
  const float* W = p.w[c_wi[j]];
  int k0 = kg * 128;
  float acc = 0.f;
  if (j != 8) {
    const float* Wp = W + (size_t)c_r0[j] * 512 * 512 + n;
#pragma unroll 16
    for (int k = k0; k < k0 + 128; ++k) acc += A[k] * Wp[(size_t)k * 512];
  } else {  // Wr1 sum over relations 0,1,2,4
    const float* W0 = W + n;
    const float* W1 = W + (size_t)1 * 512 * 512 + n;
    const float* W2 = W + (size_t)2 * 512 * 512 + n;
    const float* W4 = W + (size_t)4 * 512 * 512 + n;
#pragma unroll 8
    for (int k = k0; k < k0 + 128; ++k) {
      size_t o = (size_t)k * 512;
      acc += A[k] * (W0[o] + W1[o] + W2[o] + W4[o]);
    }
  }
  red[tid] = acc;
  __syncthreads();
  if (kg == 0) {
    float v = red[tid] + red[tid + 64] + red[tid + 128] + red[tid + 192];
    p.bt[c_bt[j]][(size_t)n * c_K[j] + c_ko[j] + f] = f2bf(v * c_sc[j]);
  }
}

// ---- batched bias folds: out[n] = s*(sum bl_i[n]) + s*sum_k bvec[k]*sum_r Wr1[..k..n] ----
struct VFPtrs { const float* bl[5]; const float* bvec[5]; const float* w; float* out[5]; };

__constant__ int   c_vi[5][4] = {{0,1,2,4},{0,1,2,4},{5,-1,-1,-1},{6,-1,-1,-1},{3,-1,-1,-1}};
__constant__ float c_vs[5]    = {0.25f,0.25f,1.f,1.f,1.f};

__global__ __launch_bounds__(256) void vecfold_multi(VFPtrs p) {
  __shared__ float red[256];
  int j = blockIdx.x >> 4, blk = blockIdx.x & 15;
  int tid = threadIdx.x;
  int n = blk * 32 + (tid & 31);
  int kg = tid >> 5;
  const float* bv = p.bvec[j];
  float a = 0.f;
  if (bv) {
    int i1 = c_vi[j][1];
    const float* W0 = p.w + (size_t)c_vi[j][0] * 512 * 512 + n;
    if (i1 < 0) {
#pragma unroll 16
      for (int k = kg * 64; k < kg * 64 + 64; ++k) a += bv[k] * W0[(size_t)k * 512];
    } else {
      const float* W1 = p.w + (size_t)c_vi[j][1] * 512 * 512 + n;
      const float* W2 = p.w + (size_t)c_vi[j][2] * 512 * 512 + n;
      const float* W3 = p.w + (size_t)c_vi[j][3] * 512 * 512 + n;
#pragma unroll 8
      for (int k = kg * 64; k < kg * 64 + 64; ++k) {
        size_t o = (size_t)k * 512;
        a += bv[k] * (W0[o] + W1[o] + W2[o] + W3[o]);
      }
    }
  }
  red[tid] = a;
  __syncthreads();
  if (kg == 0) {
    float v = 0.f;
#pragma unroll
    for (int q = 0; q < 8; ++q) v += red[(tid & 31) + q * 32];
    float bsum = p.bl[j][c_vi[j][0] * 512 + n];
    if (c_vi[j][1] >= 0) {
      bsum += p.bl[j][c_vi[j][1] * 512 + n];
      bsum += p.bl[j][c_vi[j][2] * 512 + n];
      bsum += p.bl[j][c_vi[j][3] * 512 + n];
    }
    p.out[j][n] = (v + bsum) * c_vs[j];
  }
}

// ---- CSR build ----
__global__ void hist_k(const int* __restrict__ dst, int nE, int* __restrict__ cnt) {
  int i = blockIdx.x * 256 + threadIdx.x;
  if (i < nE) atomicAdd(&cnt[dst[i]], 1);
}

__global__ void hist_range(const int* __restrict__ dst, const int* __restrict__ src, int nE,
                           int* __restrict__ cnt, int s0, int s1) {
  int i = blockIdx.x * 256 + threadIdx.x;
  if (i < nE) {
    int s = src[i];
    if (s >= s0 && s < s1) atomicAdd(&cnt[dst[i]], 1);
  }
}

__global__ void scan1_k(const int* __restrict__ in, int* __restrict__ out,
                        int* __restrict__ part, int n) {
  __shared__ int s[256];
  int t = threadIdx.x;
  int base = blockIdx.x * 1024 + t * 4;
  int x0 = 0, x1 = 0, x2 = 0, x3 = 0;
  if (base < n) x0 = in[base];
  if (base + 1 < n) x1 = in[base + 1];
  if (base + 2 < n) x2 = in[base + 2];
  if (base + 3 < n) x3 = in[base + 3];
  int tsum = x0 + x1 + x2 + x3;
  s[t] = tsum;
  __syncthreads();
  for (int off = 1; off < 256; off <<= 1) {
    int v = (t >= off) ? s[t - off] : 0;
    __syncthreads();
    s[t] += v;
    __syncthreads();
  }
  int excl = s[t] - tsum;
  if (base < n) out[base] = excl;
  if (base + 1 < n) out[base + 1] = excl + x0;
  if (base + 2 < n) out[base + 2] = excl + x0 + x1;
  if (base + 3 < n) out[base + 3] = excl + x0 + x1 + x2;
  if (t == 255) part[blockIdx.x] = s[255];
}

__global__ void scan2_k(int* __restrict__ part, int nb) {
  __shared__ int s[1024];
  int t = threadIdx.x;
  int orig = (t < nb) ? part[t] : 0;
  s[t] = orig;
  __syncthreads();
  for (int off = 1; off < 1024; off <<= 1) {
    int v = (t >= off) ? s[t - off] : 0;
    __syncthreads();
    s[t] += v;
    __syncthreads();
  }
  if (t < nb) part[t] = s[t] - orig;
}

__global__ void scan3_k(int* __restrict__ out, int* __restrict__ cursor,
                        const int* __restrict__ part, int n) {
  int i = blockIdx.x * 256 + threadIdx.x;
  if (i < n) {
    int v = out[i] + part[i >> 10];
    out[i] = v;
    cursor[i] = v;
  }
}

__global__ void fill_range(const int* __restrict__ src, const int* __restrict__ dst, int nE,
                           int* __restrict__ cursor, int* __restrict__ esrc, int s0, int s1) {
  int i = blockIdx.x * 256 + threadIdx.x;
  if (i >= nE) return;
  int s = src[i];
  if (s >= s0 && s < s1) {
    int pos = atomicAdd(&cursor[dst[i]], 1);
    esrc[pos] = s - s0;
  }
}

// ---- raw-feature segment mean + indicator (8 threads per dst row) ----
__global__ void raw_agg(const int* __restrict__ offs, const int* __restrict__ esrc,
                        const float* __restrict__ x, int F, u16* __restrict__ A1,
                        int K, int colOff, int indCol, int nd) {
  int row = blockIdx.x * 32 + (threadIdx.x >> 3);
  if (row >= nd) return;
  int j = threadIdx.x & 7;
  int e0 = offs[row], e1 = offs[row + 1];
  float acc[4] = {0.f, 0.f, 0.f, 0.f};
  for (int e = e0; e < e1; ++e) {
    int s = esrc[e];
#pragma unroll
    for (int u = 0; u < 4; ++u) {
      int f = j + u * 8;
      if (f < F) acc[u] += x[(size_t)s * F + f];
    }
  }
  float inv = (e1 > e0) ? 1.f / (float)(e1 - e0) : 0.f;
#pragma unroll
  for (int u = 0; u < 4; ++u) {
    int f = j + u * 8;
    if (f < F) A1[(size_t)row * K + colOff + f] = f2bf(acc[u] * inv);
  }
  if (j == 0) A1[(size_t)row * K + indCol] = f2bf((e1 > e0) ? 1.f : 0.f);
}

// ---- copy root raw features into A1 ----
__global__ void a1_root(const float* __restrict__ x, int rowBase, u16* __restrict__ A1,
                        int K, int rootOff, int nd, int lf) {
  int idx = blockIdx.x * 256 + threadIdx.x;
  int i = idx >> lf, f = idx & ((1 << lf) - 1);
  if (i >= nd) return;
  A1[(size_t)i * K + rootOff + f] = f2bf(x[(((size_t)(rowBase + i)) << lf) + f]);
}

// ---- gather partial segment-sums scaled by 1/full-count (wave per dst row) ----
__global__ void seg_gather(const int* __restrict__ offsF, const int* __restrict__ offsS,
                           const int* __restrict__ esrcF, const u16* __restrict__ hsrc,
                           u16* __restrict__ agg, int nd) {
  int w = blockIdx.x * 4 + (threadIdx.x >> 6);
  if (w >= nd) return;
  int l = threadIdx.x & 63;
  int e0 = offsF[w], e1 = offsF[w + 1];
  int c0 = offsS[w], c1 = offsS[w + 1];
  float inv = (c1 > c0) ? 1.f / (float)(c1 - c0) : 0.f;
  float acc[8] = {0.f, 0.f, 0.f, 0.f, 0.f, 0.f, 0.f, 0.f};
  for (int e = e0; e < e1; ++e) {
    int s = esrcF[e];
    bf16x8 v = *(const bf16x8*)&hsrc[(size_t)s * 512 + l * 8];
#pragma unroll
    for (int j = 0; j < 8; ++j) acc[j] += bf2f((u16)v[j]);
  }
  bf16x8 r;
#pragma unroll
  for (int j = 0; j < 8; ++j) r[j] = (short)f2bf(acc[j] * inv);
  *(bf16x8*)&agg[(size_t)w * 512 + l * 8] = r;
}

// ---- MFMA GEMM: C[M][512] (+)= op(A[M][K] @ BT[512][K]^T + bias), bf16 ----
// T2 XOR-swizzled LDS (rule #21: linear gload_lds dest + pre-swizzled global src + swizzled read)
template <bool ELU, bool ACC>
__global__ __launch_bounds__(256) void gemm_k(
    const u16* __restrict__ A, int K, const u16* __restrict__ BT,
    const float* __restrict__ bias, u16* __restrict__ C, int M) {
  __shared__ u16 As[128 * 64];
  __shared__ u16 Bs[128 * 64];
  int tid = threadIdx.x;
  int wid = tid >> 6, lane = tid & 63;
  int wm = wid >> 1, wn = wid & 1;
  int bm = blockIdx.x * 128, bn = blockIdx.y * 128;
  int r16 = lane & 15, hi4 = lane >> 4;
  int srow = tid >> 3;
  int scol = ((tid & 7) ^ (srow & 7)) * 8;  // pre-swizzled source column group
  int sw = r16 & 7;                          // read-side XOR key
  f32x4 acc[4][4];
#pragma unroll
  for (int i = 0; i < 4; ++i)
#pragma unroll
    for (int j = 0; j < 4; ++j) acc[i][j] = (f32x4){0.f, 0.f, 0.f, 0.f};

  for (int k0 = 0; k0 < K; k0 += 64) {
    __syncthreads();
#pragma unroll
    for (int i = 0; i < 4; ++i) {
      const u16* ga = A + (size_t)(bm + i * 32 + srow) * K + k0 + scol;
      const u16* gb = BT + (size_t)(bn + i * 32 + srow) * K + k0 + scol;
      __builtin_amdgcn_global_load_lds((gv_t*)ga, (lv_t*)(As + i * 2048 + wid * 512), 16, 0, 0);
      __builtin_amdgcn_global_load_lds((gv_t*)gb, (lv_t*)(Bs + i * 2048 + wid * 512), 16, 0, 0);
    }
    __syncthreads();
#pragma unroll
    for (int kk = 0; kk < 64; kk += 32) {
      bf16x8 af[4], bfr[4];
#pragma unroll
      for (int f = 0; f < 4; ++f) {
        int grp = (kk >> 3) + hi4;
        af[f]  = *(const bf16x8*)&As[(wm * 64 + f * 16 + r16) * 64 + ((grp ^ sw) << 3)];
        bfr[f] = *(const bf16x8*)&Bs[(wn * 64 + f * 16 + r16) * 64 + ((grp ^ sw) << 3)];
      }
#pragma unroll
      for (int mf = 0; mf < 4; ++mf)
#pragma unroll
        for (int nf = 0; nf < 4; ++nf)
          acc[mf][nf] = __builtin_amdgcn_mfma_f32_16x16x32_bf16(af[mf], bfr[nf], acc[mf][nf], 0, 0, 0);
    }
  }
#pragma unroll
  for (int mf = 0; mf < 4; ++mf) {
#pragma unroll
    for (int nf = 0; nf < 4; ++nf) {
      int c = bn + wn * 64 + nf * 16 + r16;
      float bv = bias ? bias[c] : 0.f;
#pragma unroll
      for (int j = 0; j < 4; ++j) {
        int r = bm + wm * 64 + mf * 16 + hi4 * 4 + j;
        float v = acc[mf][nf][j] + bv;
        if (ACC) v += bf2f(C[(size_t)r * 512 + c]);
        if (ELU) v = v > 0.f ? v : expm1f(v);
        C[(size_t)r * 512 + c] = f2bf(v);
      }
    }
  }
}

// ---- acc init: broadcast bias vector ----
__global__ void bcast_k(u16* __restrict__ acc, const float* __restrict__ bv, int rows) {
  int idx = blockIdx.x * 256 + threadIdx.x;
  int row = idx >> 6, c8 = (idx & 63) * 8;
  if (row >= rows) return;
  bf16x8 r;
#pragma unroll
  for (int j = 0; j < 8; ++j) r[j] = (short)f2bf(bv[c8 + j]);
  *(bf16x8*)&acc[(size_t)row * 512 + c8] = r;
}

// ---- LayerNorm in place (optional ELU first); wave per row ----
template <bool ELU>
__global__ void ln_rows(u16* __restrict__ H, const float* __restrict__ g,
                        const float* __restrict__ be, int rows) {
  int w = blockIdx.x * 4 + (threadIdx.x >> 6);
  if (w >= rows) return;
  int l = threadIdx.x & 63;
  u16* p = H + (size_t)w * 512 + l * 8;
  bf16x8 v = *(const bf16x8*)p;
  float x[8];
  float s = 0.f;
#pragma unroll
  for (int j = 0; j < 8; ++j) {
    x[j] = bf2f((u16)v[j]);
    if (ELU) x[j] = x[j] > 0.f ? x[j] : expm1f(x[j]);
    s += x[j];
  }
#pragma unroll
  for (int m = 1; m < 64; m <<= 1) s += __shfl_xor(s, m, 64);
  float mean = s * (1.f / 512.f);
  float q = 0.f;
#pragma unroll
  for (int j = 0; j < 8; ++j) { float d = x[j] - mean; q += d * d; }
#pragma unroll
  for (int m = 1; m < 64; m <<= 1) q += __shfl_xor(q, m, 64);
  float rsd = rsqrtf(q * (1.f / 512.f) + 1e-5f);
  bf16x8 r;
#pragma unroll
  for (int j = 0; j < 8; ++j) {
    int c = l * 8 + j;
    r[j] = (short)f2bf((x[j] - mean) * rsd * g[c] + be[c]);
  }
  *(bf16x8*)p = r;
}

// ---- pooling ----
DEVINL int lowb(const int* a, int n, int v) {
  int lo = 0, hi = n;
  while (lo < hi) { int m = (lo + hi) >> 1; if (a[m] < v) lo = m + 1; else hi = m; }
  return lo;
}

__global__ void pool1(const u16* __restrict__ H, const int* __restrict__ batch, int nOp,
                      float* __restrict__ pooled, int* __restrict__ cnts) {
  int g = blockIdx.x >> 3, part = blockIdx.x & 7;
  int lo = lowb(batch, nOp, g), hi = lowb(batch, nOp, g + 1);
  if (part == 0 && threadIdx.x == 0) cnts[g] = hi - lo;
  int len = hi - lo;
  int chunk = (len + 7) >> 3;
  int r0 = lo + part * chunk;
  int r1 = r0 + chunk;
  if (r1 > hi) r1 = hi;
  int t = threadIdx.x;
  float a0 = 0.f, a1 = 0.f;
  for (int r = r0; r < r1; ++r) {
    a0 += bf2f(H[(size_t)r * 512 + t]);
    a1 += bf2f(H[(size_t)r * 512 + t + 256]);
  }
  atomicAdd(&pooled[g * 512 + t], a0);
  atomicAdd(&pooled[g * 512 + t + 256], a1);
}

__global__ void pool2(const float* __restrict__ pooled, const int* __restrict__ cnts,
                      const float* __restrict__ Wout, const float* __restrict__ bout,
                      float* __restrict__ out) {
  int gg = blockIdx.x;
  int l = threadIdx.x;
  float s = 0.f;
#pragma unroll
  for (int j = 0; j < 8; ++j) {
    int c = l * 8 + j;
    s += pooled[gg * 512 + c] * Wout[c];
  }
#pragma unroll
  for (int m = 1; m < 64; m <<= 1) s += __shfl_xor(s, m, 64);
  if (l == 0) {
    int c = cnts[gg];
    if (c < 1) c = 1;
    out[gg] = s / (float)c + bout[0];
  }
}

extern "C" void kernel_launch(void* const* d_in, const int* in_sizes, int n_in,
                              void* d_out, int out_size, void* d_ws, size_t ws_size,
                              hipStream_t stream) {
  (void)in_sizes; (void)n_in; (void)out_size;
  // inputs: node feats 0=op,1=tab,2=col,3=pred
  const float* x_op   = (const float*)d_in[0];
  const float* x_tab  = (const float*)d_in[1];
  const float* x_col  = (const float*)d_in[2];
  const float* x_pred = (const float*)d_in[3];
  const float* W_op = (const float*)d_in[4],  *b_op = (const float*)d_in[5];
  const float* W_tab = (const float*)d_in[6], *b_tab = (const float*)d_in[7];
  const float* W_col = (const float*)d_in[8], *b_col = (const float*)d_in[9];
  const float* W_pred = (const float*)d_in[10], *b_pred = (const float*)d_in[11];
  const float* Wl1 = (const float*)d_in[12];
  const float* bl1 = (const float*)d_in[13];
  const float* Wr1 = (const float*)d_in[14];
  const float* Wl2 = (const float*)d_in[15];
  const float* bl2 = (const float*)d_in[16];
  const float* Wr2 = (const float*)d_in[17];
  const float* g1  = (const float*)d_in[18];
  const float* be1 = (const float*)d_in[19];
  const float* g2  = (const float*)d_in[20];
  const float* be2 = (const float*)d_in[21];
  const float* Wout = (const float*)d_in[22];
  const float* bout = (const float*)d_in[23];
  const int* SRC[7], *DST[7];
  for (int r = 0; r < 7; ++r) { SRC[r] = (const int*)d_in[24 + 2 * r]; DST[r] = (const int*)d_in[25 + 2 * r]; }
  const int* batch = (const int*)d_in[38];
  float* out = (float*)d_out;

  const int EREL[7] = {262144, 262144, 262144, 262144, 262144, 32768, 131072};
  const int CSRB[7] = {0, 131072, 262144, 393216, 458752, 589824, 622592};
  const int TOT = 753664;
  const int NOP = 131072;

  // ---- workspace layout (256 MiB budget) ----
  char* ws = (char*)d_ws;
  u16* acc    = (u16*)ws;                            // 134,217,728 : conv2_op accumulator (bf16)
  u16* hsrc   = (u16*)(ws + 134217728ull);           //  67,108,864 : recomputed layer-1 h chunk
  u16* agg    = (u16*)(ws + 201326592ull);           //  33,554,432 : [32768x512] bf16 agg chunk
  int* curFul = (int*)(ws + 201326592ull);           //   (overlay in agg: CSR-build cursor)
  u16* A1     = (u16*)(ws + 234881024ull);           //  16,777,216 : [65536x128] bf16 features
  int* offsFul= (int*)(ws + 251658240ull);           //   3,014,912 : (TOT+1) offsets
  int* esrcFul= (int*)(ws + 254673152ull);           //   5,898,240
  int* offsF  = (int*)(ws + 260571392ull);           //     524,544 : filtered CSR (131073)
  int* curF   = (int*)(ws + 261095936ull);           //     524,544
  int* esrcF  = (int*)(ws + 261620480ull);           //   1,048,576
  u16* BT2_0  = (u16*)(ws + 262669056ull);           //   5x524,288 : layer-2 weights [512x512]
  u16* BT2_1  = BT2_0 + 262144;
  u16* BT2_2  = BT2_1 + 262144;
  u16* BT2_4  = BT2_2 + 262144;
  u16* BT2rt  = BT2_4 + 262144;
  u16* BT1op  = (u16*)(ws + 265290496ull);           //      65,536 : [512x64]
  u16* BT1tab = (u16*)(ws + 265356032ull);           //      65,536
  u16* BT1col = (u16*)(ws + 265421568ull);           //     131,072 : [512x128]
  u16* BT1pr  = (u16*)(ws + 265552640ull);           //      65,536
  float* b1op = (float*)(ws + 265618176ull);         //   5x2048 bias vecs
  float* b1tab = b1op + 512, *b1col = b1op + 1024, *b1pr = b1op + 1536, *b2vec = b1op + 2048;
  float* pooled = (float*)(ws + 265628416ull);       //     131,072
  int* cnts     = (int*)(ws + 265759488ull);         //         256
  int* part     = (int*)(ws + 265759744ull);         //       4,096
  const size_t WS_NEED = 265763840ull;
  if (ws_size < WS_NEED) { probe_k<<<1, 64, 0, stream>>>(out, (float)ws_size); return; }

  // ---- A. full CSR for all 7 relations ----
  hipMemsetAsync(curFul, 0, (size_t)(TOT + 1) * 4, stream);
  for (int r = 0; r < 7; ++r)
    hist_k<<<(EREL[r] + 255) / 256, 256, 0, stream>>>(DST[r], EREL[r], curFul + CSRB[r]);
  scan1_k<<<737, 256, 0, stream>>>(curFul, offsFul, part, TOT + 1);
  scan2_k<<<1, 1024, 0, stream>>>(part, 737);
  scan3_k<<<2945, 256, 0, stream>>>(offsFul, curFul, part, TOT + 1);
  for (int r = 0; r < 7; ++r)
    fill_range<<<(EREL[r] + 255) / 256, 256, 0, stream>>>(SRC[r], DST[r], EREL[r],
                                                          curFul + CSRB[r], esrcFul, 0, 1 << 30);

  // ---- B. weight folding ----
  // layer 2 (dst=op only): conv2 = 1/4 * [sum_r agg_r@Wl2_r + bl2_r] + 1/4 * h1op@sum(Wr2_r)
  pack_wt<<<1024, 256, 0, stream>>>(Wl2, 0, -1, -1, -1, BT2_0, 512, 0, 0.25f);
  pack_wt<<<1024, 256, 0, stream>>>(Wl2, 1, -1, -1, -1, BT2_1, 512, 0, 0.25f);
  pack_wt<<<1024, 256, 0, stream>>>(Wl2, 2, -1, -1, -1, BT2_2, 512, 0, 0.25f);
  pack_wt<<<1024, 256, 0, stream>>>(Wl2, 4, -1, -1, -1, BT2_4, 512, 0, 0.25f);
  pack_wt<<<1024, 256, 0, stream>>>(Wr2, 0, 1, 2, 4, BT2rt, 512, 0, 0.25f);
  // layer 1 folded into raw-feature space: one batched launch (18 jobs).
  hipMemsetAsync(BT1op, 0, 65536 + 65536 + 131072 + 65536, stream);
  FoldPtrs fp;
  fp.a[0] = W_tab; fp.a[1] = b_tab; fp.a[2] = W_pred; fp.a[3] = b_pred;
  fp.a[4] = W_col; fp.a[5] = b_col; fp.a[6] = W_op;   fp.a[7] = b_op;
  fp.w[0] = Wl1;   fp.w[1] = Wr1;
  fp.bt[0] = BT1op; fp.bt[1] = BT1tab; fp.bt[2] = BT1col; fp.bt[3] = BT1pr;
  fold_multi<<<1256, 256, 0, stream>>>(fp);
  VFPtrs vp;
  vp.bl[0] = bl2; vp.bl[1] = bl1; vp.bl[2] = bl1; vp.bl[3] = bl1; vp.bl[4] = bl1;
  vp.bvec[0] = nullptr; vp.bvec[1] = b_op; vp.bvec[2] = b_tab; vp.bvec[3] = b_col; vp.bvec[4] = b_pred;
  vp.w = Wr1;
  vp.out[0] = b2vec; vp.out[1] = b1op; vp.out[2] = b1tab; vp.out[3] = b1col; vp.out[4] = b1pr;
  vecfold_multi<<<80, 256, 0, stream>>>(vp);

  // ---- C. init acc with layer-2 bias ----
  bcast_k<<<32768, 256, 0, stream>>>(acc, b2vec, NOP);

  // helper: filtered CSR build for relation rel with src in [s0,s1)
  auto build_filt = [&](int rel, int s0, int s1) {
    hipMemsetAsync(curF, 0, 131073ull * 4, stream);
    hist_range<<<(EREL[rel] + 255) / 256, 256, 0, stream>>>(DST[rel], SRC[rel], EREL[rel], curF, s0, s1);
    scan1_k<<<129, 256, 0, stream>>>(curF, offsF, part, 131073);
    scan2_k<<<1, 1024, 0, stream>>>(part, 129);
    scan3_k<<<513, 256, 0, stream>>>(offsF, curF, part, 131073);
    fill_range<<<(EREL[rel] + 255) / 256, 256, 0, stream>>>(SRC[rel], DST[rel], EREL[rel], curF, esrcF, s0, s1);
  };
  // helper: 4x agg-chunk + accumulate-GEMM over all op dst rows
  auto rel_pass = [&](const int* oF, const int* oS, const int* eF, const u16* bt) {
    for (int c = 0; c < 4; ++c) {
      int c0 = c * 32768;
      seg_gather<<<8192, 256, 0, stream>>>(oF + c0, oS + c0, eF, hsrc, agg, 32768);
      gemm_k<false, true><<<dim3(256, 4), 256, 0, stream>>>(agg, 512, bt, nullptr,
                                                            acc + (size_t)c0 * 512, 32768);
    }
  };

  // ---- D. relation 0: tab -> op ----
  hipMemsetAsync(A1, 0, 32768ull * 64 * 2, stream);
  raw_agg<<<1024, 256, 0, stream>>>(offsFul + CSRB[5], esrcFul, x_tab, 2, A1, 64, 0, 2, 32768);
  a1_root<<<256, 256, 0, stream>>>(x_tab, 0, A1, 64, 3, 32768, 1);
  gemm_k<true, false><<<dim3(256, 4), 256, 0, stream>>>(A1, 64, BT1tab, b1tab, hsrc, 32768);
  ln_rows<false><<<8192, 256, 0, stream>>>(hsrc, g1, be1, 32768);
  rel_pass(offsFul + CSRB[0], offsFul + CSRB[0], esrcFul, BT2_0);

  // ---- E. relation 1: pred -> op ----
  hipMemsetAsync(A1, 0, 65536ull * 64 * 2, stream);
  raw_agg<<<2048, 256, 0, stream>>>(offsFul + CSRB[3], esrcFul, x_col, 32, A1, 64, 0, 32, 65536);
  a1_root<<<1024, 256, 0, stream>>>(x_pred, 0, A1, 64, 33, 65536, 2);
  gemm_k<true, false><<<dim3(512, 4), 256, 0, stream>>>(A1, 64, BT1pr, b1pr, hsrc, 65536);
  ln_rows<false><<<16384, 256, 0, stream>>>(hsrc, g1, be1, 65536);
  rel_pass(offsFul + CSRB[1], offsFul + CSRB[1], esrcFul, BT2_1);

  // ---- F. relation 2: col -> op (col recomputed in halves) ----
  for (int h = 0; h < 2; ++h) {
    int s0 = h * 65536, s1 = s0 + 65536;
    hipMemsetAsync(A1, 0, 65536ull * 128 * 2, stream);
    raw_agg<<<2048, 256, 0, stream>>>(offsFul + CSRB[6] + s0, esrcFul, x_col, 32, A1, 128, 0, 32, 65536);
    a1_root<<<8192, 256, 0, stream>>>(x_col, s0, A1, 128, 33, 65536, 5);
    gemm_k<true, false><<<dim3(512, 4), 256, 0, stream>>>(A1, 128, BT1col, b1col, hsrc, 65536);
    ln_rows<false><<<16384, 256, 0, stream>>>(hsrc, g1, be1, 65536);
    build_filt(2, s0, s1);
    rel_pass(offsF, offsFul + CSRB[2], esrcF, BT2_2);
  }

  // ---- G. op halves: root GEMM + relation 4 (op -> op) ----
  for (int h = 0; h < 2; ++h) {
    int s0 = h * 65536, s1 = s0 + 65536;
    hipMemsetAsync(A1, 0, 65536ull * 64 * 2, stream);
    raw_agg<<<2048, 256, 0, stream>>>(offsFul + CSRB[0] + s0, esrcFul, x_tab, 2, A1, 64, 0, 2, 65536);
    raw_agg<<<2048, 256, 0, stream>>>(offsFul + CSRB[1] + s0, esrcFul, x_pred, 4, A1, 64, 3, 7, 65536);
    raw_agg<<<2048, 256, 0, stream>>>(offsFul + CSRB[2] + s0, esrcFul, x_col, 32, A1, 64, 8, 40, 65536);
    raw_agg<<<2048, 256, 0, stream>>>(offsFul + CSRB[4] + s0, esrcFul, x_op, 4, A1, 64, 41, 45, 65536);
    a1_root<<<1024, 256, 0, stream>>>(x_op, s0, A1, 64, 46, 65536, 2);
    gemm_k<true, false><<<dim3(512, 4), 256, 0, stream>>>(A1, 64, BT1op, b1op, hsrc, 65536);
    ln_rows<false><<<16384, 256, 0, stream>>>(hsrc, g1, be1, 65536);
    // root: acc[s0..s1) += h1op_half @ BT2rt
    gemm_k<false, true><<<dim3(512, 4), 256, 0, stream>>>(hsrc, 512, BT2rt, nullptr,
                                                          acc + (size_t)s0 * 512, 65536);
    build_filt(4, s0, s1);
    rel_pass(offsF, offsFul + CSRB[4], esrcF, BT2_4);
  }

  // ---- H. ELU + LN2 in place, pool, output ----
  ln_rows<true><<<32768, 256, 0, stream>>>(acc, g2, be2, NOP);
  hipMemsetAsync(pooled, 0, 64 * 512 * 4, stream);
  pool1<<<512, 256, 0, stream>>>(acc, batch, NOP, pooled, cnts);
  pool2<<<64, 64, 0, stream>>>(pooled, cnts, Wout, bout, out);
}

// Round 6
// 2198.094 us; speedup vs baseline: 2.0960x; 1.1295x over previous
//
#include <hip/hip_runtime.h>
#include <hip/hip_bf16.h>

typedef unsigned short u16;
typedef __attribute__((ext_vector_type(8))) short bf16x8;
typedef __attribute__((ext_vector_type(4))) float f32x4;

typedef __attribute__((address_space(1))) const void gv_t;  // global
typedef __attribute__((address_space(3))) void lv_t;        // LDS

#define DEVINL __device__ __forceinline__

DEVINL float bf2f(u16 s) { union { unsigned u; float f; } v; v.u = ((unsigned)s) << 16; return v.f; }
DEVINL u16 f2bf(float f) {
  union { float f; unsigned u; } v; v.f = f;
  return (u16)((v.u + 0x7FFFu + ((v.u >> 16) & 1u)) >> 16);
}

// ---- ws probe ----
__global__ void probe_k(float* __restrict__ out, float v) { out[threadIdx.x] = v; }

// ---- batched layer-2 packs: 5 jobs x 1024 blocks ----
struct PackPtrs { const float* wl2; const float* wr2; u16* bt[5]; };
__global__ __launch_bounds__(256) void pack_multi(PackPtrs p) {
  int j = blockIdx.x >> 10;
  int idx = (blockIdx.x & 1023) * 256 + threadIdx.x;
  int k = idx >> 9, n = idx & 511;
  float v;
  if (j < 4) {
    int r = (j == 3) ? 4 : j;
    v = p.wl2[((size_t)r * 512 + k) * 512 + n];
  } else {
    size_t o = (size_t)k * 512 + n;
    v = p.wr2[o] + p.wr2[o + 262144] + p.wr2[o + 524288] + p.wr2[o + 1048576];
  }
  p.bt[j][(size_t)n * 512 + k] = f2bf(v * 0.25f);
}

// ================= batched layer-1 weight folding (18 jobs) =================
struct FoldPtrs { const float* a[8]; const float* w[2]; u16* bt[4]; };
__constant__ int   c_off[19] = {0,16,24,56,64,320,328,360,368,400,416,424,440,696,704,960,1216,1224,1256};
__constant__ int   c_ai[18]  = {0,1,2,3,4,5,6,7,6, 0,1,0, 4,5,4, 4,5,2};
__constant__ int   c_wi[18]  = {0,0,0,0,0,0,0,0,1, 0,0,1, 0,0,1, 0,0,1};
__constant__ int   c_r0[18]  = {0,0,1,1,2,2,4,4,0, 5,5,5, 6,6,6, 3,3,3};
__constant__ float c_sc[18]  = {0.25f,0.25f,0.25f,0.25f,0.25f,0.25f,0.25f,0.25f,0.25f,
                                1.f,1.f,1.f, 1.f,1.f,1.f, 1.f,1.f,1.f};
__constant__ int   c_bt[18]  = {0,0,0,0,0,0,0,0,0, 1,1,1, 2,2,2, 3,3,3};
__constant__ int   c_K[18]   = {64,64,64,64,64,64,64,64,64, 64,64,64, 128,128,128, 64,64,64};
__constant__ int   c_ko[18]  = {0,2,3,7,8,40,41,45,46, 0,2,3, 0,32,33, 0,32,33};

__global__ __launch_bounds__(256) void fold_multi(FoldPtrs p) {
  __shared__ float red[256];
  int b = blockIdx.x;
  int j = 0;
#pragma unroll
  for (int t = 1; t < 18; ++t) j += (b >= c_off[t]);
  int rel = b - c_off[j];
  int f = rel >> 3, nb = rel & 7;
  int tid = threadIdx.x;
  int n = nb * 64 + (tid & 63);
  int kg = tid >> 6;
  const float* A = p.a[c_ai[j]] + (size_t)f * 512;
  const float* W = p.w[c_wi[j]];
  int k0 = kg * 128;
  float acc = 0.f;
  if (j != 8) {
    const float* Wp = W + (size_t)c_r0[j] * 512 * 512 + n;
#pragma unroll 16
    for (int k = k0; k < k0 + 128; ++k) acc += A[k] * Wp[(size_t)k * 512];
  } else {
    const float* W0 = W + n;
    const float* W1 = W + (size_t)262144 + n;
    const float* W2 = W + (size_t)524288 + n;
    const float* W4 = W + (size_t)1048576 + n;
#pragma unroll 8
    for (int k = k0; k < k0 + 128; ++k) {
      size_t o = (size_t)k * 512;
      acc += A[k] * (W0[o] + W1[o] + W2[o] + W4[o]);
    }
  }
  red[tid] = acc;
  __syncthreads();
  if (kg == 0) {
    float v = red[tid] + red[tid + 64] + red[tid + 128] + red[tid + 192];
    p.bt[c_bt[j]][(size_t)n * c_K[j] + c_ko[j] + f] = f2bf(v * c_sc[j]);
  }
}

// ---- batched bias folds ----
struct VFPtrs { const float* bl[5]; const float* bvec[5]; const float* w; float* out[5]; };
__constant__ int   c_vi[5][4] = {{0,1,2,4},{0,1,2,4},{5,-1,-1,-1},{6,-1,-1,-1},{3,-1,-1,-1}};
__constant__ float c_vs[5]    = {0.25f,0.25f,1.f,1.f,1.f};

__global__ __launch_bounds__(256) void vecfold_multi(VFPtrs p) {
  __shared__ float red[256];
  int j = blockIdx.x >> 4, blk = blockIdx.x & 15;
  int tid = threadIdx.x;
  int n = blk * 32 + (tid & 31);
  int kg = tid >> 5;
  const float* bv = p.bvec[j];
  float a = 0.f;
  if (bv) {
    int i1 = c_vi[j][1];
    const float* W0 = p.w + (size_t)c_vi[j][0] * 262144 + n;
    if (i1 < 0) {
#pragma unroll 16
      for (int k = kg * 64; k < kg * 64 + 64; ++k) a += bv[k] * W0[(size_t)k * 512];
    } else {
      const float* W1 = p.w + (size_t)c_vi[j][1] * 262144 + n;
      const float* W2 = p.w + (size_t)c_vi[j][2] * 262144 + n;
      const float* W3 = p.w + (size_t)c_vi[j][3] * 262144 + n;
#pragma unroll 8
      for (int k = kg * 64; k < kg * 64 + 64; ++k) {
        size_t o = (size_t)k * 512;
        a += bv[k] * (W0[o] + W1[o] + W2[o] + W3[o]);
      }
    }
  }
  red[tid] = a;
  __syncthreads();
  if (kg == 0) {
    float v = 0.f;
#pragma unroll
    for (int q = 0; q < 8; ++q) v += red[(tid & 31) + q * 32];
    float bsum = p.bl[j][c_vi[j][0] * 512 + n];
    if (c_vi[j][1] >= 0) {
      bsum += p.bl[j][c_vi[j][1] * 512 + n];
      bsum += p.bl[j][c_vi[j][2] * 512 + n];
      bsum += p.bl[j][c_vi[j][3] * 512 + n];
    }
    p.out[j][n] = (v + bsum) * c_vs[j];
  }
}

// ================= CSR build (batched) =================
struct EdgePtrs { const int* dst[7]; const int* src[7]; };
__constant__ int c_hoff[8]  = {0,1024,2048,3072,4096,5120,5248,5760};
__constant__ int c_hbase[7] = {0,131072,262144,393216,458752,589824,622592};
__constant__ int c_hne[7]   = {262144,262144,262144,262144,262144,32768,131072};

__global__ __launch_bounds__(256) void hist_multi(EdgePtrs p, int* __restrict__ cnt) {
  int b = blockIdx.x;
  int j = 0;
#pragma unroll
  for (int t = 1; t < 7; ++t) j += (b >= c_hoff[t]);
  int i = (b - c_hoff[j]) * 256 + threadIdx.x;
  if (i < c_hne[j]) atomicAdd(&cnt[c_hbase[j] + p.dst[j][i]], 1);
}

__global__ __launch_bounds__(256) void fill_multi(EdgePtrs p, int* __restrict__ cursor,
                                                  int* __restrict__ esrc) {
  int b = blockIdx.x;
  int j = 0;
#pragma unroll
  for (int t = 1; t < 7; ++t) j += (b >= c_hoff[t]);
  int i = (b - c_hoff[j]) * 256 + threadIdx.x;
  if (i < c_hne[j]) {
    int pos = atomicAdd(&cursor[c_hbase[j] + p.dst[j][i]], 1);
    esrc[pos] = p.src[j][i];
  }
}

// filtered CSRs: 4 jobs (rel2 h0, rel2 h1, rel4 h0, rel4 h1), 1024 blocks each
struct FiltPtrs { const int* dst[2]; const int* src[2]; };
__global__ __launch_bounds__(256) void histf_multi(FiltPtrs p, int* __restrict__ cnt) {
  int j = blockIdx.x >> 10;
  int rel = j >> 1, s0 = (j & 1) * 65536;
  int i = (blockIdx.x & 1023) * 256 + threadIdx.x;
  int s = p.src[rel][i];
  if (s >= s0 && s < s0 + 65536) atomicAdd(&cnt[j * 131072 + p.dst[rel][i]], 1);
}
__global__ __launch_bounds__(256) void fillf_multi(FiltPtrs p, int* __restrict__ cursor,
                                                   int* __restrict__ esrc) {
  int j = blockIdx.x >> 10;
  int rel = j >> 1, s0 = (j & 1) * 65536;
  int i = (blockIdx.x & 1023) * 256 + threadIdx.x;
  int s = p.src[rel][i];
  if (s >= s0 && s < s0 + 65536) {
    int pos = atomicAdd(&cursor[j * 131072 + p.dst[rel][i]], 1);
    esrc[pos] = s - s0;
  }
}

__global__ void scan1_k(const int* __restrict__ in, int* __restrict__ out,
                        int* __restrict__ part, int n) {
  __shared__ int s[256];
  int t = threadIdx.x;
  int base = blockIdx.x * 1024 + t * 4;
  int x0 = 0, x1 = 0, x2 = 0, x3 = 0;
  if (base < n) x0 = in[base];
  if (base + 1 < n) x1 = in[base + 1];
  if (base + 2 < n) x2 = in[base + 2];
  if (base + 3 < n) x3 = in[base + 3];
  int tsum = x0 + x1 + x2 + x3;
  s[t] = tsum;
  __syncthreads();
  for (int off = 1; off < 256; off <<= 1) {
    int v = (t >= off) ? s[t - off] : 0;
    __syncthreads();
    s[t] += v;
    __syncthreads();
  }
  int excl = s[t] - tsum;
  if (base < n) out[base] = excl;
  if (base + 1 < n) out[base + 1] = excl + x0;
  if (base + 2 < n) out[base + 2] = excl + x0 + x1;
  if (base + 3 < n) out[base + 3] = excl + x0 + x1 + x2;
  if (t == 255) part[blockIdx.x] = s[255];
}

__global__ void scan2_k(int* __restrict__ part, int nb) {
  __shared__ int s[1024];
  int t = threadIdx.x;
  int orig = (t < nb) ? part[t] : 0;
  s[t] = orig;
  __syncthreads();
  for (int off = 1; off < 1024; off <<= 1) {
    int v = (t >= off) ? s[t - off] : 0;
    __syncthreads();
    s[t] += v;
    __syncthreads();
  }
  if (t < nb) part[t] = s[t] - orig;
}

__global__ void scan3_k(int* __restrict__ out, int* __restrict__ cursor,
                        const int* __restrict__ part, int n) {
  int i = blockIdx.x * 256 + threadIdx.x;
  if (i < n) {
    int v = out[i] + part[i >> 10];
    out[i] = v;
    cursor[i] = v;
  }
}

// ---- raw-feature segment mean + indicator (8 threads per dst row) ----
__global__ void raw_agg(const int* __restrict__ offs, const int* __restrict__ esrc,
                        const float* __restrict__ x, int F, u16* __restrict__ A1,
                        int K, int colOff, int indCol, int nd) {
  int row = blockIdx.x * 32 + (threadIdx.x >> 3);
  if (row >= nd) return;
  int j = threadIdx.x & 7;
  int e0 = offs[row], e1 = offs[row + 1];
  float acc[4] = {0.f, 0.f, 0.f, 0.f};
  for (int e = e0; e < e1; ++e) {
    int s = esrc[e];
#pragma unroll
    for (int u = 0; u < 4; ++u) {
      int f = j + u * 8;
      if (f < F) acc[u] += x[(size_t)s * F + f];
    }
  }
  float inv = (e1 > e0) ? 1.f / (float)(e1 - e0) : 0.f;
#pragma unroll
  for (int u = 0; u < 4; ++u) {
    int f = j + u * 8;
    if (f < F) A1[(size_t)row * K + colOff + f] = f2bf(acc[u] * inv);
  }
  if (j == 0) A1[(size_t)row * K + indCol] = f2bf((e1 > e0) ? 1.f : 0.f);
}

// batched version for stage G: 4 jobs x 2048 blocks, K=64, nd=65536
struct RawPtrs { const int* offs; const int* esrc; const float* x[4]; u16* A1; };
__constant__ int c_gF[4]    = {2,4,32,4};
__constant__ int c_gco[4]   = {0,3,8,41};
__constant__ int c_gic[4]   = {2,7,40,45};
__constant__ int c_gcsrb[4] = {0,131072,262144,458752};

__global__ __launch_bounds__(256) void raw_multi(RawPtrs p, int s0) {
  int j = blockIdx.x >> 11;
  int row = (blockIdx.x & 2047) * 32 + (threadIdx.x >> 3);
  int jj = threadIdx.x & 7;
  const int* offs = p.offs + c_gcsrb[j] + s0;
  const float* x = p.x[j];
  int F = c_gF[j];
  int e0 = offs[row], e1 = offs[row + 1];
  float acc[4] = {0.f, 0.f, 0.f, 0.f};
  for (int e = e0; e < e1; ++e) {
    int s = p.esrc[e];
#pragma unroll
    for (int u = 0; u < 4; ++u) {
      int f = jj + u * 8;
      if (f < F) acc[u] += x[(size_t)s * F + f];
    }
  }
  float inv = (e1 > e0) ? 1.f / (float)(e1 - e0) : 0.f;
#pragma unroll
  for (int u = 0; u < 4; ++u) {
    int f = jj + u * 8;
    if (f < F) p.A1[(size_t)row * 64 + c_gco[j] + f] = f2bf(acc[u] * inv);
  }
  if (jj == 0) p.A1[(size_t)row * 64 + c_gic[j]] = f2bf((e1 > e0) ? 1.f : 0.f);
}

// ---- copy root raw features into A1 ----
__global__ void a1_root(const float* __restrict__ x, int rowBase, u16* __restrict__ A1,
                        int K, int rootOff, int nd, int lf) {
  int idx = blockIdx.x * 256 + threadIdx.x;
  int i = idx >> lf, f = idx & ((1 << lf) - 1);
  if (i >= nd) return;
  A1[(size_t)i * K + rootOff + f] = f2bf(x[(((size_t)(rowBase + i)) << lf) + f]);
}

// ---- gather partial segment-sums scaled by 1/full-count (wave per dst row) ----
__global__ void seg_gather(const int* __restrict__ offsF, const int* __restrict__ offsS,
                           const int* __restrict__ esrcF, const u16* __restrict__ hsrc,
                           u16* __restrict__ agg, int nd) {
  int w = blockIdx.x * 4 + (threadIdx.x >> 6);
  if (w >= nd) return;
  int l = threadIdx.x & 63;
  int e0 = offsF[w], e1 = offsF[w + 1];
  int c0 = offsS[w], c1 = offsS[w + 1];
  float inv = (c1 > c0) ? 1.f / (float)(c1 - c0) : 0.f;
  float acc[8] = {0.f, 0.f, 0.f, 0.f, 0.f, 0.f, 0.f, 0.f};
  for (int e = e0; e < e1; ++e) {
    int s = esrcF[e];
    bf16x8 v = *(const bf16x8*)&hsrc[(size_t)s * 512 + l * 8];
#pragma unroll
    for (int j = 0; j < 8; ++j) acc[j] += bf2f((u16)v[j]);
  }
  bf16x8 r;
#pragma unroll
  for (int j = 0; j < 8; ++j) r[j] = (short)f2bf(acc[j] * inv);
  *(bf16x8*)&agg[(size_t)w * 512 + l * 8] = r;
}

// ---- MFMA GEMM: C[M][512] (+)= op(A[M][K] @ BT[512][K]^T + bias), bf16 ----
template <bool ELU, bool ACC, int K>
__global__ __launch_bounds__(256) void gemm_k(
    const u16* __restrict__ A, const u16* __restrict__ BT,
    const float* __restrict__ bias, u16* __restrict__ C, int M) {
  __shared__ u16 As[128 * 64];
  __shared__ u16 Bs[128 * 64];
  int tid = threadIdx.x;
  int wid = tid >> 6, lane = tid & 63;
  int wm = wid >> 1, wn = wid & 1;
  int bm = blockIdx.x * 128, bn = blockIdx.y * 128;
  int r16 = lane & 15, hi4 = lane >> 4;
  int srow = tid >> 3;
  int scol = ((tid & 7) ^ (srow & 7)) * 8;  // pre-swizzled source column group
  int sw = r16 & 7;                          // read-side XOR key
  f32x4 acc[4][4];
#pragma unroll
  for (int i = 0; i < 4; ++i)
#pragma unroll
    for (int j = 0; j < 4; ++j) acc[i][j] = (f32x4){0.f, 0.f, 0.f, 0.f};

#pragma unroll
  for (int k0 = 0; k0 < K; k0 += 64) {
    __syncthreads();
#pragma unroll
    for (int i = 0; i < 4; ++i) {
      const u16* ga = A + (size_t)(bm + i * 32 + srow) * K + k0 + scol;
      const u16* gb = BT + (size_t)(bn + i * 32 + srow) * K + k0 + scol;
      __builtin_amdgcn_global_load_lds((gv_t*)ga, (lv_t*)(As + i * 2048 + wid * 512), 16, 0, 0);
      __builtin_amdgcn_global_load_lds((gv_t*)gb, (lv_t*)(Bs + i * 2048 + wid * 512), 16, 0, 0);
    }
    __syncthreads();
#pragma unroll
    for (int kk = 0; kk < 64; kk += 32) {
      bf16x8 af[4], bfr[4];
#pragma unroll
      for (int f = 0; f < 4; ++f) {
        int grp = (kk >> 3) + hi4;
        af[f]  = *(const bf16x8*)&As[(wm * 64 + f * 16 + r16) * 64 + ((grp ^ sw) << 3)];
        bfr[f] = *(const bf16x8*)&Bs[(wn * 64 + f * 16 + r16) * 64 + ((grp ^ sw) << 3)];
      }
#pragma unroll
      for (int mf = 0; mf < 4; ++mf)
#pragma unroll
        for (int nf = 0; nf < 4; ++nf)
          acc[mf][nf] = __builtin_amdgcn_mfma_f32_16x16x32_bf16(af[mf], bfr[nf], acc[mf][nf], 0, 0, 0);
    }
  }
#pragma unroll
  for (int mf = 0; mf < 4; ++mf) {
#pragma unroll
    for (int nf = 0; nf < 4; ++nf) {
      int c = bn + wn * 64 + nf * 16 + r16;
      float bv = bias ? bias[c] : 0.f;
#pragma unroll
      for (int j = 0; j < 4; ++j) {
        int r = bm + wm * 64 + mf * 16 + hi4 * 4 + j;
        float v = acc[mf][nf][j] + bv;
        if (ACC) v += bf2f(C[(size_t)r * 512 + c]);
        if (ELU) v = v > 0.f ? v : expm1f(v);
        C[(size_t)r * 512 + c] = f2bf(v);
      }
    }
  }
}

// ---- LayerNorm in place (wave per row) ----
__global__ void ln_rows(u16* __restrict__ H, const float* __restrict__ g,
                        const float* __restrict__ be, int rows) {
  int w = blockIdx.x * 4 + (threadIdx.x >> 6);
  if (w >= rows) return;
  int l = threadIdx.x & 63;
  u16* p = H + (size_t)w * 512 + l * 8;
  bf16x8 v = *(const bf16x8*)p;
  float x[8];
  float s = 0.f;
#pragma unroll
  for (int j = 0; j < 8; ++j) { x[j] = bf2f((u16)v[j]); s += x[j]; }
#pragma unroll
  for (int m = 1; m < 64; m <<= 1) s += __shfl_xor(s, m, 64);
  float mean = s * (1.f / 512.f);
  float q = 0.f;
#pragma unroll
  for (int j = 0; j < 8; ++j) { float d = x[j] - mean; q += d * d; }
#pragma unroll
  for (int m = 1; m < 64; m <<= 1) q += __shfl_xor(q, m, 64);
  float rsd = rsqrtf(q * (1.f / 512.f) + 1e-5f);
  bf16x8 r;
#pragma unroll
  for (int j = 0; j < 8; ++j) {
    int c = l * 8 + j;
    r[j] = (short)f2bf((x[j] - mean) * rsd * g[c] + be[c]);
  }
  *(bf16x8*)p = r;
}

// ---- fused ELU + LN2 + pool partial-sum (wave per row, vectorized) ----
DEVINL int lowb(const int* a, int n, int v) {
  int lo = 0, hi = n;
  while (lo < hi) { int m = (lo + hi) >> 1; if (a[m] < v) lo = m + 1; else hi = m; }
  return lo;
}

__global__ __launch_bounds__(256) void pool1v(const u16* __restrict__ H,
                                              const int* __restrict__ batch, int nOp,
                                              const float* __restrict__ g2,
                                              const float* __restrict__ be2,
                                              float* __restrict__ pooled,
                                              int* __restrict__ cnts) {
  __shared__ float red[4][512];
  int gr = blockIdx.x >> 4, part = blockIdx.x & 15;
  int lo = lowb(batch, nOp, gr), hi = lowb(batch, nOp, gr + 1);
  if (part == 0 && threadIdx.x == 0) cnts[gr] = hi - lo;
  int len = hi - lo;
  int chunk = (len + 15) >> 4;
  int r0 = lo + part * chunk;
  int r1 = r0 + chunk;
  if (r1 > hi) r1 = hi;
  int wv = threadIdx.x >> 6, l = threadIdx.x & 63;
  float a[8] = {0.f, 0.f, 0.f, 0.f, 0.f, 0.f, 0.f, 0.f};
  float gv[8], bv[8];
#pragma unroll
  for (int j = 0; j < 8; ++j) { gv[j] = g2[l * 8 + j]; bv[j] = be2[l * 8 + j]; }
  for (int r = r0 + wv; r < r1; r += 4) {
    bf16x8 v = *(const bf16x8*)&H[(size_t)r * 512 + l * 8];
    float x[8];
    float s = 0.f;
#pragma unroll
    for (int j = 0; j < 8; ++j) {
      x[j] = bf2f((u16)v[j]);
      x[j] = x[j] > 0.f ? x[j] : expm1f(x[j]);
      s += x[j];
    }
#pragma unroll
    for (int m = 1; m < 64; m <<= 1) s += __shfl_xor(s, m, 64);
    float mean = s * (1.f / 512.f);
    float q = 0.f;
#pragma unroll
    for (int j = 0; j < 8; ++j) { float d = x[j] - mean; q += d * d; }
#pragma unroll
    for (int m = 1; m < 64; m <<= 1) q += __shfl_xor(q, m, 64);
    float rsd = rsqrtf(q * (1.f / 512.f) + 1e-5f);
#pragma unroll
    for (int j = 0; j < 8; ++j) a[j] += (x[j] - mean) * rsd * gv[j] + bv[j];
  }
#pragma unroll
  for (int j = 0; j < 8; ++j) red[wv][l * 8 + j] = a[j];
  __syncthreads();
  if (wv == 0) {
#pragma unroll
    for (int j = 0; j < 8; ++j) {
      int c = l * 8 + j;
      float s = red[0][c] + red[1][c] + red[2][c] + red[3][c];
      atomicAdd(&pooled[gr * 512 + c], s);
    }
  }
}

__global__ void pool2(const float* __restrict__ pooled, const int* __restrict__ cnts,
                      const float* __restrict__ Wout, const float* __restrict__ bout,
                      float* __restrict__ out) {
  int gg = blockIdx.x;
  int l = threadIdx.x;
  float s = 0.f;
#pragma unroll
  for (int j = 0; j < 8; ++j) {
    int c = l * 8 + j;
    s += pooled[gg * 512 + c] * Wout[c];
  }
#pragma unroll
  for (int m = 1; m < 64; m <<= 1) s += __shfl_xor(s, m, 64);
  if (l == 0) {
    int c = cnts[gg];
    if (c < 1) c = 1;
    out[gg] = s / (float)c + bout[0];
  }
}

extern "C" void kernel_launch(void* const* d_in, const int* in_sizes, int n_in,
                              void* d_out, int out_size, void* d_ws, size_t ws_size,
                              hipStream_t stream) {
  (void)in_sizes; (void)n_in; (void)out_size;
  const float* x_op   = (const float*)d_in[0];
  const float* x_tab  = (const float*)d_in[1];
  const float* x_col  = (const float*)d_in[2];
  const float* x_pred = (const float*)d_in[3];
  const float* W_op = (const float*)d_in[4],  *b_op = (const float*)d_in[5];
  const float* W_tab = (const float*)d_in[6], *b_tab = (const float*)d_in[7];
  const float* W_col = (const float*)d_in[8], *b_col = (const float*)d_in[9];
  const float* W_pred = (const float*)d_in[10], *b_pred = (const float*)d_in[11];
  const float* Wl1 = (const float*)d_in[12];
  const float* bl1 = (const float*)d_in[13];
  const float* Wr1 = (const float*)d_in[14];
  const float* Wl2 = (const float*)d_in[15];
  const float* bl2 = (const float*)d_in[16];
  const float* Wr2 = (const float*)d_in[17];
  const float* g1  = (const float*)d_in[18];
  const float* be1 = (const float*)d_in[19];
  const float* g2  = (const float*)d_in[20];
  const float* be2 = (const float*)d_in[21];
  const float* Wout = (const float*)d_in[22];
  const float* bout = (const float*)d_in[23];
  const int* SRC[7], *DST[7];
  for (int r = 0; r < 7; ++r) { SRC[r] = (const int*)d_in[24 + 2 * r]; DST[r] = (const int*)d_in[25 + 2 * r]; }
  const int* batch = (const int*)d_in[38];
  float* out = (float*)d_out;

  const int CSRB[7] = {0, 131072, 262144, 393216, 458752, 589824, 622592};
  const int TOT = 753664;
  const int NOP = 131072;

  // ---- workspace layout (256 MiB) ----
  char* ws = (char*)d_ws;
  u16* acc     = (u16*)ws;                          // 134,217,728
  u16* hsrc    = (u16*)(ws + 134217728ull);         //  67,108,864
  u16* agg     = (u16*)(ws + 201326592ull);         //  33,554,432 (CSR cursors overlay)
  int* curFul  = (int*)(ws + 201326592ull);         //  (TOT+1)*4 = 3,014,660
  int* curAll  = (int*)(ws + 204341504ull);         //  524,289*4 = 2,097,156
  u16* A1      = (u16*)(ws + 234881024ull);         //  16,777,216
  int* offsFul = (int*)(ws + 251658240ull);         //   3,014,912
  int* esrcFul = (int*)(ws + 254673152ull);         //   5,898,240
  int* offsAll = (int*)(ws + 260571392ull);         //   2,097,408
  int* esrcAll = (int*)(ws + 262668800ull);         //   2,097,152
  u16* BT2_0   = (u16*)(ws + 264765952ull);         //   5 x 524,288
  u16* BT2_1   = BT2_0 + 262144;
  u16* BT2_2   = BT2_1 + 262144;
  u16* BT2_4   = BT2_2 + 262144;
  u16* BT2rt   = BT2_4 + 262144;
  u16* BT1op   = (u16*)(ws + 267387392ull);         //      65,536
  u16* BT1tab  = (u16*)(ws + 267452928ull);         //      65,536
  u16* BT1col  = (u16*)(ws + 267518464ull);         //     131,072
  u16* BT1pr   = (u16*)(ws + 267649536ull);         //      65,536
  float* b1op  = (float*)(ws + 267715072ull);       //   5 x 2048
  float* b1tab = b1op + 512, *b1col = b1op + 1024, *b1pr = b1op + 1536, *b2vec = b1op + 2048;
  float* pooled = (float*)(ws + 267725312ull);      //     131,072
  int* cnts     = (int*)(ws + 267856384ull);        //         256
  int* part     = (int*)(ws + 267856640ull);        //       4,096
  const size_t WS_NEED = 267860736ull;
  if (ws_size < WS_NEED) { probe_k<<<1, 64, 0, stream>>>(out, (float)ws_size); return; }

  // ---- A. CSR builds: full (7 rels) + filtered (rel2/rel4 x halves), batched ----
  hipMemsetAsync(curFul, 0, 3014912ull + 2097156ull, stream);  // curFul + curAll contiguous
  EdgePtrs ep;
  for (int r = 0; r < 7; ++r) { ep.dst[r] = DST[r]; ep.src[r] = SRC[r]; }
  hist_multi<<<5760, 256, 0, stream>>>(ep, curFul);
  scan1_k<<<737, 256, 0, stream>>>(curFul, offsFul, part, TOT + 1);
  scan2_k<<<1, 1024, 0, stream>>>(part, 737);
  scan3_k<<<2945, 256, 0, stream>>>(offsFul, curFul, part, TOT + 1);
  fill_multi<<<5760, 256, 0, stream>>>(ep, curFul, esrcFul);
  FiltPtrs fpt;
  fpt.dst[0] = DST[2]; fpt.src[0] = SRC[2];
  fpt.dst[1] = DST[4]; fpt.src[1] = SRC[4];
  histf_multi<<<4096, 256, 0, stream>>>(fpt, curAll);
  scan1_k<<<513, 256, 0, stream>>>(curAll, offsAll, part, 524289);
  scan2_k<<<1, 1024, 0, stream>>>(part, 513);
  scan3_k<<<2049, 256, 0, stream>>>(offsAll, curAll, part, 524289);
  fillf_multi<<<4096, 256, 0, stream>>>(fpt, curAll, esrcAll);

  // ---- B. weight folding ----
  PackPtrs pp;
  pp.wl2 = Wl2; pp.wr2 = Wr2;
  pp.bt[0] = BT2_0; pp.bt[1] = BT2_1; pp.bt[2] = BT2_2; pp.bt[3] = BT2_4; pp.bt[4] = BT2rt;
  pack_multi<<<5120, 256, 0, stream>>>(pp);
  hipMemsetAsync(BT1op, 0, 65536 + 65536 + 131072 + 65536, stream);
  FoldPtrs fp;
  fp.a[0] = W_tab; fp.a[1] = b_tab; fp.a[2] = W_pred; fp.a[3] = b_pred;
  fp.a[4] = W_col; fp.a[5] = b_col; fp.a[6] = W_op;   fp.a[7] = b_op;
  fp.w[0] = Wl1;   fp.w[1] = Wr1;
  fp.bt[0] = BT1op; fp.bt[1] = BT1tab; fp.bt[2] = BT1col; fp.bt[3] = BT1pr;
  fold_multi<<<1256, 256, 0, stream>>>(fp);
  VFPtrs vp;
  vp.bl[0] = bl2; vp.bl[1] = bl1; vp.bl[2] = bl1; vp.bl[3] = bl1; vp.bl[4] = bl1;
  vp.bvec[0] = nullptr; vp.bvec[1] = b_op; vp.bvec[2] = b_tab; vp.bvec[3] = b_col; vp.bvec[4] = b_pred;
  vp.w = Wr1;
  vp.out[0] = b2vec; vp.out[1] = b1op; vp.out[2] = b1tab; vp.out[3] = b1col; vp.out[4] = b1pr;
  vecfold_multi<<<80, 256, 0, stream>>>(vp);

  // helper: 4x agg-chunk + accumulate-GEMM over all op dst rows
  auto rel_pass = [&](const int* oF, const int* oS, const int* eF, const u16* bt, bool first) {
    for (int c = 0; c < 4; ++c) {
      int c0 = c * 32768;
      seg_gather<<<8192, 256, 0, stream>>>(oF + c0, oS + c0, eF, hsrc, agg, 32768);
      if (first)
        gemm_k<false, false, 512><<<dim3(256, 4), 256, 0, stream>>>(agg, bt, b2vec,
                                                                    acc + (size_t)c0 * 512, 32768);
      else
        gemm_k<false, true, 512><<<dim3(256, 4), 256, 0, stream>>>(agg, bt, nullptr,
                                                                   acc + (size_t)c0 * 512, 32768);
    }
  };

  // ---- D. relation 0: tab -> op (first pass, writes acc with bias) ----
  hipMemsetAsync(A1, 0, 65536ull * 64 * 2, stream);  // covers D + E (K=64 layouts)
  raw_agg<<<1024, 256, 0, stream>>>(offsFul + CSRB[5], esrcFul, x_tab, 2, A1, 64, 0, 2, 32768);
  a1_root<<<256, 256, 0, stream>>>(x_tab, 0, A1, 64, 3, 32768, 1);
  gemm_k<true, false, 64><<<dim3(256, 4), 256, 0, stream>>>(A1, BT1tab, b1tab, hsrc, 32768);
  ln_rows<<<8192, 256, 0, stream>>>(hsrc, g1, be1, 32768);
  rel_pass(offsFul + CSRB[0], offsFul + CSRB[0], esrcFul, BT2_0, true);

  // ---- E. relation 1: pred -> op ----
  raw_agg<<<2048, 256, 0, stream>>>(offsFul + CSRB[3], esrcFul, x_col, 32, A1, 64, 0, 32, 65536);
  a1_root<<<1024, 256, 0, stream>>>(x_pred, 0, A1, 64, 33, 65536, 2);
  gemm_k<true, false, 64><<<dim3(512, 4), 256, 0, stream>>>(A1, BT1pr, b1pr, hsrc, 65536);
  ln_rows<<<16384, 256, 0, stream>>>(hsrc, g1, be1, 65536);
  rel_pass(offsFul + CSRB[1], offsFul + CSRB[1], esrcFul, BT2_1, false);

  // ---- F. relation 2: col -> op (col recomputed in halves) ----
  hipMemsetAsync(A1, 0, 65536ull * 128 * 2, stream);
  for (int h = 0; h < 2; ++h) {
    int s0 = h * 65536;
    raw_agg<<<2048, 256, 0, stream>>>(offsFul + CSRB[6] + s0, esrcFul, x_col, 32, A1, 128, 0, 32, 65536);
    a1_root<<<8192, 256, 0, stream>>>(x_col, s0, A1, 128, 33, 65536, 5);
    gemm_k<true, false, 128><<<dim3(512, 4), 256, 0, stream>>>(A1, BT1col, b1col, hsrc, 65536);
    ln_rows<<<16384, 256, 0, stream>>>(hsrc, g1, be1, 65536);
    rel_pass(offsAll + h * 131072, offsFul + CSRB[2], esrcAll, BT2_2, false);
  }

  // ---- G. op halves: root GEMM + relation 4 (op -> op) ----
  hipMemsetAsync(A1, 0, 65536ull * 64 * 2, stream);
  for (int h = 0; h < 2; ++h) {
    int s0 = h * 65536;
    RawPtrs rp;
    rp.offs = offsFul; rp.esrc = esrcFul; rp.A1 = A1;
    rp.x[0] = x_tab; rp.x[1] = x_pred; rp.x[2] = x_col; rp.x[3] = x_op;
    raw_multi<<<8192, 256, 0, stream>>>(rp, s0);
    a1_root<<<1024, 256, 0, stream>>>(x_op, s0, A1, 64, 46, 65536, 2);
    gemm_k<true, false, 64><<<dim3(512, 4), 256, 0, stream>>>(A1, BT1op, b1op, hsrc, 65536);
    ln_rows<<<16384, 256, 0, stream>>>(hsrc, g1, be1, 65536);
    gemm_k<false, true, 512><<<dim3(512, 4), 256, 0, stream>>>(hsrc, BT2rt, nullptr,
                                                               acc + (size_t)s0 * 512, 65536);
    rel_pass(offsAll + (2 + h) * 131072, offsFul + CSRB[4], esrcAll, BT2_4, false);
  }

  // ---- H. fused ELU + LN2 + pool, then output ----
  hipMemsetAsync(pooled, 0, 64 * 512 * 4, stream);
  pool1v<<<1024, 256, 0, stream>>>(acc, batch, NOP, g2, be2, pooled, cnts);
  pool2<<<64, 64, 0, stream>>>(pooled, cnts, Wout, bout, out);
}